// Round 8
// baseline (844.613 us; speedup 1.0000x reference)
//
#include <hip/hip_runtime.h>

// GCN 2-layer. Edges bucket-partitioned by dst, counting-sorted per bucket by
// (dst_local, src_chunk). Aggregation is XCD-feature-sliced: blockIdx%8 (XCD
// round-robin proxy) selects a feature slice (6 floats for NC=48, 4 for NC=32)
// so each XCD gathers from a 2.4/1.6 MB slice of Hs that stays L2-resident --
// Hs is fetched once device-wide instead of once per XCD (r7: FETCH=8x19.2MB).
// GEMMs: register-tiled 2xCPT, X from global, W in LDS (r5 lesson: transposed-X
// LDS staging + full unroll => 850 MB scratch spill; do not reintroduce).
// out = GCNConv(relu(GCNConv(x,W1,b1)), W2, b2); N=100k, E=1.6M, 64->48->32.

#define NN 100000
#define NE 1600000
#define NPB 128                         // nodes per bucket
#define NBUCK ((NN + NPB - 1) / NPB)    // 782
#define PBITS 17                        // src fits in 17 bits
#define PMASK ((1 << PBITS) - 1)
#define CHB 3                           // log2 src chunks
#define CHS 14                          // chunk = src >> 14
#define NKEY (NPB << CHB)               // 1024 sort keys per bucket
#define PART_B 512
#define EPT 32
#define PART_G ((NE + PART_B * EPT - 1) / (PART_B * EPT))   // 98
#define CAP 4096                        // LDS staging per bucket (mean 2048)
#define NXCD 8

__global__ void k_zero_b(int* __restrict__ bcnt) {
    int i = threadIdx.x;
    if (i < NBUCK) bcnt[i] = 0;
}

// per-bucket edge histogram (LDS-staged, int atomics only)
__global__ void k_hist(const int* __restrict__ dst, int* __restrict__ bcnt) {
    __shared__ int h[NBUCK];
    for (int i = threadIdx.x; i < NBUCK; i += blockDim.x) h[i] = 0;
    __syncthreads();
    int base = blockIdx.x * (PART_B * EPT);
    for (int k = 0; k < EPT; ++k) {
        int e = base + k * PART_B + threadIdx.x;
        if (e < NE) atomicAdd(&h[dst[e] >> 7], 1);
    }
    __syncthreads();
    for (int i = threadIdx.x; i < NBUCK; i += blockDim.x)
        if (h[i]) atomicAdd(&bcnt[i], h[i]);
}

// single-block exclusive scan over 782 bucket counts; row_ptr[NN] = NE
__global__ void k_scan(const int* __restrict__ bcnt, int* __restrict__ bbase,
                       int* __restrict__ gcursor, int* __restrict__ row_ptr) {
    __shared__ int sm[1024];
    int t = threadIdx.x;
    int v = (t < NBUCK) ? bcnt[t] : 0;
    sm[t] = v; __syncthreads();
    for (int off = 1; off < 1024; off <<= 1) {
        int xv = (t >= off) ? sm[t - off] : 0;
        __syncthreads();
        sm[t] += xv;
        __syncthreads();
    }
    if (t < NBUCK) { int ex = sm[t] - v; bbase[t] = ex; gcursor[t] = ex; }
    if (t == 0) { bbase[NBUCK] = NE; row_ptr[NN] = NE; }
}

// partition edges into bucket order; packed = src | (dst_local << PBITS)
__global__ void k_part(const int* __restrict__ src, const int* __restrict__ dst,
                       int* __restrict__ gcursor, int* __restrict__ packed) {
    __shared__ int h[NBUCK];
    __shared__ int base[NBUCK];
    for (int i = threadIdx.x; i < NBUCK; i += blockDim.x) h[i] = 0;
    __syncthreads();
    int ebase = blockIdx.x * (PART_B * EPT);
    for (int k = 0; k < EPT; ++k) {
        int e = ebase + k * PART_B + threadIdx.x;
        if (e < NE) atomicAdd(&h[dst[e] >> 7], 1);
    }
    __syncthreads();
    for (int i = threadIdx.x; i < NBUCK; i += blockDim.x) {
        int c = h[i];
        if (c) base[i] = atomicAdd(&gcursor[i], c);
        h[i] = 0;
    }
    __syncthreads();
    for (int k = 0; k < EPT; ++k) {
        int e = ebase + k * PART_B + threadIdx.x;
        if (e < NE) {
            int d = dst[e];
            int b = d >> 7;
            int r = atomicAdd(&h[b], 1);
            packed[base[b] + r] = src[e] | ((d & (NPB - 1)) << PBITS);
        }
    }
}

// per-bucket counting sort by (dst_local, src_chunk) -> srcsort, row_ptr, dinv.
__global__ void k_bsort(const int* __restrict__ packed, const int* __restrict__ bbase,
                        int* __restrict__ srcsort, int* __restrict__ row_ptr,
                        float* __restrict__ dinv) {
    __shared__ int stage[CAP];          // 16 KB
    __shared__ int cnt[NKEY];           // 4 KB  (counts -> excl starts -> cursors)
    __shared__ int tsum[256];           // 1 KB
    int tid = threadIdx.x, b = blockIdx.x;
    int e0 = bbase[b], e1 = bbase[b + 1], sz = e1 - e0;
    for (int i = tid; i < NKEY; i += 256) cnt[i] = 0;
    __syncthreads();
    for (int i = tid; i < sz; i += 256) {
        int w = packed[e0 + i];
        if (i < CAP) stage[i] = w;
        int key = ((w >> PBITS) << CHB) | ((w & PMASK) >> CHS);
        atomicAdd(&cnt[key], 1);
    }
    __syncthreads();
    // exclusive scan over NKEY=1024: each thread owns 4 consecutive keys
    int k0 = tid * 4;
    int c0 = cnt[k0], c1 = cnt[k0 + 1], c2 = cnt[k0 + 2], c3 = cnt[k0 + 3];
    int loc = c0 + c1 + c2 + c3;
    tsum[tid] = loc;
    __syncthreads();
    for (int off = 1; off < 256; off <<= 1) {
        int v = (tid >= off) ? tsum[tid - off] : 0;
        __syncthreads();
        tsum[tid] += v;
        __syncthreads();
    }
    int base = tsum[tid] - loc;         // exclusive across threads
    cnt[k0]     = base;
    cnt[k0 + 1] = base + c0;
    cnt[k0 + 2] = base + c0 + c1;
    cnt[k0 + 3] = base + c0 + c1 + c2;
    __syncthreads();
    // row starts / degrees BEFORE cursors get bumped
    if (tid < NPB) {
        int node = b * NPB + tid;
        int rs = cnt[tid << CHB];
        int re = (tid == NPB - 1) ? sz : cnt[(tid + 1) << CHB];
        if (node < NN) {
            row_ptr[node] = e0 + rs;
            dinv[node] = rsqrtf((float)(re - rs + 1));   // +1 self-loop
        }
    }
    __syncthreads();
    for (int i = tid; i < sz; i += 256) {
        int w = (i < CAP) ? stage[i] : packed[e0 + i];
        int key = ((w >> PBITS) << CHB) | ((w & PMASK) >> CHS);
        int p = atomicAdd(&cnt[key], 1);
        srcsort[e0 + p] = w & PMASK;
    }
}

// Register-tiled GEMM: Hs[M,NC] = f(X[M,K]) @ W[K,NC] * dinv[row]
template <int K, int NC, int CPT, bool RELU_IN>
__global__ __launch_bounds__(256) void
k_gemm(const float* __restrict__ X, const float* __restrict__ W,
       const float* __restrict__ bin, const float* __restrict__ dinv,
       float* __restrict__ H, int M) {
    constexpr int CG = NC / CPT;         // 4 col groups
    constexpr int MT = (256 / CG) * 2;   // 128 rows per block
    constexpr int KF4 = K / 4;
    __shared__ float w[K * NC];
    __shared__ float bb[K];
    int tid = threadIdx.x;
    int R0 = blockIdx.x * MT;
    for (int i = tid; i < K * NC; i += 256) w[i] = W[i];
    if (RELU_IN)
        for (int i = tid; i < K; i += 256) bb[i] = bin[i];
    __syncthreads();

    int tc = tid % CG, tr = tid / CG;
    int r0 = R0 + 2 * tr, r1 = r0 + 1;
    int c0 = tc * CPT;
    bool ok0 = r0 < M, ok1 = r1 < M;
    const float4* X4 = (const float4*)X;
    const float4 z4 = make_float4(0.f, 0.f, 0.f, 0.f);

    float acc[2][CPT];
#pragma unroll
    for (int rr = 0; rr < 2; ++rr)
#pragma unroll
        for (int j = 0; j < CPT; ++j) acc[rr][j] = 0.f;

#pragma unroll 2
    for (int k4 = 0; k4 < KF4; ++k4) {
        float4 xa = ok0 ? X4[(size_t)r0 * KF4 + k4] : z4;
        float4 xb = ok1 ? X4[(size_t)r1 * KF4 + k4] : z4;
        float ar[4] = {xa.x, xa.y, xa.z, xa.w};
        float br[4] = {xb.x, xb.y, xb.z, xb.w};
#pragma unroll
        for (int j = 0; j < 4; ++j) {
            float va = ar[j], vb = br[j];
            if (RELU_IN) {
                float bv = bb[4 * k4 + j];
                va = fmaxf(va + bv, 0.f);
                vb = fmaxf(vb + bv, 0.f);
            }
#pragma unroll
            for (int q = 0; q < CPT / 4; ++q) {
                float4 wv = *(const float4*)&w[(4 * k4 + j) * NC + c0 + 4 * q];
                acc[0][q*4+0] = fmaf(va, wv.x, acc[0][q*4+0]);
                acc[0][q*4+1] = fmaf(va, wv.y, acc[0][q*4+1]);
                acc[0][q*4+2] = fmaf(va, wv.z, acc[0][q*4+2]);
                acc[0][q*4+3] = fmaf(va, wv.w, acc[0][q*4+3]);
                acc[1][q*4+0] = fmaf(vb, wv.x, acc[1][q*4+0]);
                acc[1][q*4+1] = fmaf(vb, wv.y, acc[1][q*4+1]);
                acc[1][q*4+2] = fmaf(vb, wv.z, acc[1][q*4+2]);
                acc[1][q*4+3] = fmaf(vb, wv.w, acc[1][q*4+3]);
            }
        }
    }
#pragma unroll
    for (int rr = 0; rr < 2; ++rr) {
        int gr = r0 + rr;
        if (gr >= M) continue;
        float d = dinv[gr];
#pragma unroll
        for (int q = 0; q < CPT / 4; ++q) {
            float4 o;
            o.x = acc[rr][q*4+0] * d; o.y = acc[rr][q*4+1] * d;
            o.z = acc[rr][q*4+2] * d; o.w = acc[rr][q*4+3] * d;
            ((float4*)H)[((size_t)gr * NC + c0) / 4 + q] = o;
        }
    }
}

// XCD-sliced aggregation, NC=48: g = blockIdx%8 selects 6-float slice.
// thread = one node's slice; per-XCD gather set = 100k*24B = 2.4 MB (L2-resident).
template <bool BIAS>
__global__ void k_agg48(const float* __restrict__ Hs, const int* __restrict__ row_ptr,
                        const int* __restrict__ srcsort, const float* __restrict__ dinv,
                        const float* __restrict__ bias, float* __restrict__ out) {
    int g = blockIdx.x & (NXCD - 1);
    int nb = blockIdx.x >> 3;
    int r = nb * blockDim.x + threadIdx.x;
    if (r >= NN) return;
    int cbase = g * 6;
    const float* hr = Hs + (size_t)r * 48 + cbase;
    float a0 = hr[0], a1 = hr[1], a2 = hr[2], a3 = hr[3], a4 = hr[4], a5 = hr[5];
    int e0 = row_ptr[r], e1 = row_ptr[r + 1];
    for (int e = e0; e < e1; ++e) {
        int s = srcsort[e];
        const float* hs = Hs + (size_t)s * 48 + cbase;
        float2 v0 = *(const float2*)(hs);
        float2 v1 = *(const float2*)(hs + 2);
        float2 v2 = *(const float2*)(hs + 4);
        a0 += v0.x; a1 += v0.y; a2 += v1.x; a3 += v1.y; a4 += v2.x; a5 += v2.y;
    }
    float d = dinv[r];
    a0 *= d; a1 *= d; a2 *= d; a3 *= d; a4 *= d; a5 *= d;
    if (BIAS) {
        const float* bf = bias + cbase;
        a0 += bf[0]; a1 += bf[1]; a2 += bf[2]; a3 += bf[3]; a4 += bf[4]; a5 += bf[5];
    }
    float* o = out + (size_t)r * 48 + cbase;
    *(float2*)(o)     = make_float2(a0, a1);
    *(float2*)(o + 2) = make_float2(a2, a3);
    *(float2*)(o + 4) = make_float2(a4, a5);
}

// XCD-sliced aggregation, NC=32: g = blockIdx%8 selects 4-float slice (1.6 MB/XCD).
template <bool BIAS>
__global__ void k_agg32(const float* __restrict__ Hs, const int* __restrict__ row_ptr,
                        const int* __restrict__ srcsort, const float* __restrict__ dinv,
                        const float* __restrict__ bias, float* __restrict__ out) {
    int g = blockIdx.x & (NXCD - 1);
    int nb = blockIdx.x >> 3;
    int r = nb * blockDim.x + threadIdx.x;
    if (r >= NN) return;
    const float4* H4 = (const float4*)Hs;
    float4 a = H4[(size_t)r * 8 + g];
    float ax = a.x, ay = a.y, az = a.z, aw = a.w;
    int e0 = row_ptr[r], e1 = row_ptr[r + 1];
    for (int e = e0; e < e1; ++e) {
        int s = srcsort[e];
        float4 v = H4[(size_t)s * 8 + g];
        ax += v.x; ay += v.y; az += v.z; aw += v.w;
    }
    float d = dinv[r];
    ax *= d; ay *= d; az *= d; aw *= d;
    if (BIAS) {
        float4 bv = ((const float4*)bias)[g];
        ax += bv.x; ay += bv.y; az += bv.z; aw += bv.w;
    }
    ((float4*)out)[(size_t)r * 8 + g] = make_float4(ax, ay, az, aw);
}

extern "C" void kernel_launch(void* const* d_in, const int* in_sizes, int n_in,
                              void* d_out, int out_size, void* d_ws, size_t ws_size,
                              hipStream_t stream) {
    const float* x  = (const float*)d_in[0];
    const int*   ei = (const int*)d_in[1];   // [2,NE] int32
    const float* W1 = (const float*)d_in[2];
    const float* b1 = (const float*)d_in[3];
    const float* W2 = (const float*)d_in[4];
    const float* b2 = (const float*)d_in[5];
    float* out = (float*)d_out;

    const int* src = ei;
    const int* dst = ei + NE;

    char* p = (char*)d_ws;
    auto take = [&](size_t elems) { void* q = p; p += ((elems * 4 + 255) & ~255ull); return q; };
    int*   bcnt    = (int*)take(NBUCK);
    int*   bbase   = (int*)take(NBUCK + 1);
    int*   gcursor = (int*)take(NBUCK);
    int*   row_ptr = (int*)take(NN + 1);
    float* dinv    = (float*)take(NN);
    int*   srcsort = (int*)take(NE);
    float* Hs      = (float*)take((size_t)NN * 48);
    float* agg1    = (float*)take((size_t)NN * 48);
    int*   packed  = (int*)agg1;   // alias: packed dead before agg1 is written
    float* Hs2     = Hs;           // Hs dead after agg1

    const int B = 256;
    const int GB = (NN + 127) / 128;          // 782 gemm blocks
    const int AB = ((NN + B - 1) / B) * NXCD; // 391*8 = 3128 agg blocks
    // --- dst-sort of edges ---
    k_zero_b<<<1, 1024, 0, stream>>>(bcnt);
    k_hist<<<PART_G, PART_B, 0, stream>>>(dst, bcnt);
    k_scan<<<1, 1024, 0, stream>>>(bcnt, bbase, gcursor, row_ptr);
    k_part<<<PART_G, PART_B, 0, stream>>>(src, dst, gcursor, packed);
    k_bsort<<<NBUCK, 256, 0, stream>>>(packed, bbase, srcsort, row_ptr, dinv);

    // --- layer 1 ---
    k_gemm<64, 48, 12, false><<<GB, 256, 0, stream>>>(x, W1, nullptr, dinv, Hs, NN);
    k_agg48<false><<<AB, B, 0, stream>>>(Hs, row_ptr, srcsort, dinv, nullptr, agg1);

    // --- layer 2 (bias1+relu fused into GEMM input read) ---
    k_gemm<48, 32, 8, true><<<GB, 256, 0, stream>>>(agg1, W2, b1, dinv, Hs2, NN);
    k_agg32<true><<<AB, B, 0, stream>>>(Hs2, row_ptr, srcsort, dinv, b2, out);
}

// Round 9
// 263.676 us; speedup vs baseline: 3.2032x; 3.2032x over previous
//
#include <hip/hip_runtime.h>
#include <hip/hip_fp16.h>

// GCN 2-layer. Edges bucket-partitioned by dst, counting-sorted per bucket by
// (dst_local, src_chunk) for L2-friendly monotone gather sweeps (r7 structure).
// Aggregation gathers from an fp16 copy of the transformed features (halves the
// random-line traffic: the r7 limiter was 8 XCDs x full-Hs re-fetch at the
// ~3 TB/s random-line ceiling). Accumulation + final outputs stay fp32.
// r8 lesson: feature-slicing without contiguous slice layout explodes line
// traffic (FETCH 1.13 GB) -- working sets are measured in 64B lines.
// r5 lesson: transposed-X LDS staging + full unroll => 850 MB scratch spill.
// out = GCNConv(relu(GCNConv(x,W1,b1)), W2, b2); N=100k, E=1.6M, 64->48->32.

#define NN 100000
#define NE 1600000
#define NPB 128                         // nodes per bucket
#define NBUCK ((NN + NPB - 1) / NPB)    // 782
#define PBITS 17                        // src fits in 17 bits
#define PMASK ((1 << PBITS) - 1)
#define CHB 3                           // log2 src chunks
#define CHS 14                          // chunk = src >> 14
#define NKEY (NPB << CHB)               // 1024 sort keys per bucket
#define PART_B 512
#define EPT 32
#define PART_G ((NE + PART_B * EPT - 1) / (PART_B * EPT))   // 98
#define CAP 4096                        // LDS staging per bucket (mean 2048)

struct alignas(8) half4 { __half2 lo, hi; };

__global__ void k_zero_b(int* __restrict__ bcnt) {
    int i = threadIdx.x;
    if (i < NBUCK) bcnt[i] = 0;
}

// per-bucket edge histogram (LDS-staged, int atomics only)
__global__ void k_hist(const int* __restrict__ dst, int* __restrict__ bcnt) {
    __shared__ int h[NBUCK];
    for (int i = threadIdx.x; i < NBUCK; i += blockDim.x) h[i] = 0;
    __syncthreads();
    int base = blockIdx.x * (PART_B * EPT);
    for (int k = 0; k < EPT; ++k) {
        int e = base + k * PART_B + threadIdx.x;
        if (e < NE) atomicAdd(&h[dst[e] >> 7], 1);
    }
    __syncthreads();
    for (int i = threadIdx.x; i < NBUCK; i += blockDim.x)
        if (h[i]) atomicAdd(&bcnt[i], h[i]);
}

// single-block exclusive scan over 782 bucket counts; row_ptr[NN] = NE
__global__ void k_scan(const int* __restrict__ bcnt, int* __restrict__ bbase,
                       int* __restrict__ gcursor, int* __restrict__ row_ptr) {
    __shared__ int sm[1024];
    int t = threadIdx.x;
    int v = (t < NBUCK) ? bcnt[t] : 0;
    sm[t] = v; __syncthreads();
    for (int off = 1; off < 1024; off <<= 1) {
        int xv = (t >= off) ? sm[t - off] : 0;
        __syncthreads();
        sm[t] += xv;
        __syncthreads();
    }
    if (t < NBUCK) { int ex = sm[t] - v; bbase[t] = ex; gcursor[t] = ex; }
    if (t == 0) { bbase[NBUCK] = NE; row_ptr[NN] = NE; }
}

// partition edges into bucket order; packed = src | (dst_local << PBITS)
__global__ void k_part(const int* __restrict__ src, const int* __restrict__ dst,
                       int* __restrict__ gcursor, int* __restrict__ packed) {
    __shared__ int h[NBUCK];
    __shared__ int base[NBUCK];
    for (int i = threadIdx.x; i < NBUCK; i += blockDim.x) h[i] = 0;
    __syncthreads();
    int ebase = blockIdx.x * (PART_B * EPT);
    for (int k = 0; k < EPT; ++k) {
        int e = ebase + k * PART_B + threadIdx.x;
        if (e < NE) atomicAdd(&h[dst[e] >> 7], 1);
    }
    __syncthreads();
    for (int i = threadIdx.x; i < NBUCK; i += blockDim.x) {
        int c = h[i];
        if (c) base[i] = atomicAdd(&gcursor[i], c);
        h[i] = 0;
    }
    __syncthreads();
    for (int k = 0; k < EPT; ++k) {
        int e = ebase + k * PART_B + threadIdx.x;
        if (e < NE) {
            int d = dst[e];
            int b = d >> 7;
            int r = atomicAdd(&h[b], 1);
            packed[base[b] + r] = src[e] | ((d & (NPB - 1)) << PBITS);
        }
    }
}

// per-bucket counting sort by (dst_local, src_chunk) -> srcsort, row_ptr, dinv.
__global__ void k_bsort(const int* __restrict__ packed, const int* __restrict__ bbase,
                        int* __restrict__ srcsort, int* __restrict__ row_ptr,
                        float* __restrict__ dinv) {
    __shared__ int stage[CAP];          // 16 KB
    __shared__ int cnt[NKEY];           // 4 KB  (counts -> excl starts -> cursors)
    __shared__ int tsum[256];           // 1 KB
    int tid = threadIdx.x, b = blockIdx.x;
    int e0 = bbase[b], e1 = bbase[b + 1], sz = e1 - e0;
    for (int i = tid; i < NKEY; i += 256) cnt[i] = 0;
    __syncthreads();
    for (int i = tid; i < sz; i += 256) {
        int w = packed[e0 + i];
        if (i < CAP) stage[i] = w;
        int key = ((w >> PBITS) << CHB) | ((w & PMASK) >> CHS);
        atomicAdd(&cnt[key], 1);
    }
    __syncthreads();
    // exclusive scan over NKEY=1024: each thread owns 4 consecutive keys
    int k0 = tid * 4;
    int c0 = cnt[k0], c1 = cnt[k0 + 1], c2 = cnt[k0 + 2], c3 = cnt[k0 + 3];
    int loc = c0 + c1 + c2 + c3;
    tsum[tid] = loc;
    __syncthreads();
    for (int off = 1; off < 256; off <<= 1) {
        int v = (tid >= off) ? tsum[tid - off] : 0;
        __syncthreads();
        tsum[tid] += v;
        __syncthreads();
    }
    int base = tsum[tid] - loc;         // exclusive across threads
    cnt[k0]     = base;
    cnt[k0 + 1] = base + c0;
    cnt[k0 + 2] = base + c0 + c1;
    cnt[k0 + 3] = base + c0 + c1 + c2;
    __syncthreads();
    // row starts / degrees BEFORE cursors get bumped
    if (tid < NPB) {
        int node = b * NPB + tid;
        int rs = cnt[tid << CHB];
        int re = (tid == NPB - 1) ? sz : cnt[(tid + 1) << CHB];
        if (node < NN) {
            row_ptr[node] = e0 + rs;
            dinv[node] = rsqrtf((float)(re - rs + 1));   // +1 self-loop
        }
    }
    __syncthreads();
    for (int i = tid; i < sz; i += 256) {
        int w = (i < CAP) ? stage[i] : packed[e0 + i];
        int key = ((w >> PBITS) << CHB) | ((w & PMASK) >> CHS);
        int p = atomicAdd(&cnt[key], 1);
        srcsort[e0 + p] = w & PMASK;
    }
}

// Register-tiled GEMM: Hh[M,NC] = half( f(X[M,K]) @ W[K,NC] * dinv[row] )
// f = relu(x + bin) when RELU_IN. Block = 256 thr = 128-row tile.
// X float4 from global (L1 broadcast), W float4 from LDS, bounded unroll.
template <int K, int NC, int CPT, bool RELU_IN>
__global__ __launch_bounds__(256) void
k_gemm(const float* __restrict__ X, const float* __restrict__ W,
       const float* __restrict__ bin, const float* __restrict__ dinv,
       __half* __restrict__ Hh, int M) {
    constexpr int CG = NC / CPT;         // 4 col groups
    constexpr int MT = (256 / CG) * 2;   // 128 rows per block
    constexpr int KF4 = K / 4;
    __shared__ float w[K * NC];
    __shared__ float bb[K];
    int tid = threadIdx.x;
    int R0 = blockIdx.x * MT;
    for (int i = tid; i < K * NC; i += 256) w[i] = W[i];
    if (RELU_IN)
        for (int i = tid; i < K; i += 256) bb[i] = bin[i];
    __syncthreads();

    int tc = tid % CG, tr = tid / CG;
    int r0 = R0 + 2 * tr, r1 = r0 + 1;
    int c0 = tc * CPT;
    bool ok0 = r0 < M, ok1 = r1 < M;
    const float4* X4 = (const float4*)X;
    const float4 z4 = make_float4(0.f, 0.f, 0.f, 0.f);

    float acc[2][CPT];
#pragma unroll
    for (int rr = 0; rr < 2; ++rr)
#pragma unroll
        for (int j = 0; j < CPT; ++j) acc[rr][j] = 0.f;

#pragma unroll 2
    for (int k4 = 0; k4 < KF4; ++k4) {
        float4 xa = ok0 ? X4[(size_t)r0 * KF4 + k4] : z4;
        float4 xb = ok1 ? X4[(size_t)r1 * KF4 + k4] : z4;
        float ar[4] = {xa.x, xa.y, xa.z, xa.w};
        float br[4] = {xb.x, xb.y, xb.z, xb.w};
#pragma unroll
        for (int j = 0; j < 4; ++j) {
            float va = ar[j], vb = br[j];
            if (RELU_IN) {
                float bv = bb[4 * k4 + j];
                va = fmaxf(va + bv, 0.f);
                vb = fmaxf(vb + bv, 0.f);
            }
#pragma unroll
            for (int q = 0; q < CPT / 4; ++q) {
                float4 wv = *(const float4*)&w[(4 * k4 + j) * NC + c0 + 4 * q];
                acc[0][q*4+0] = fmaf(va, wv.x, acc[0][q*4+0]);
                acc[0][q*4+1] = fmaf(va, wv.y, acc[0][q*4+1]);
                acc[0][q*4+2] = fmaf(va, wv.z, acc[0][q*4+2]);
                acc[0][q*4+3] = fmaf(va, wv.w, acc[0][q*4+3]);
                acc[1][q*4+0] = fmaf(vb, wv.x, acc[1][q*4+0]);
                acc[1][q*4+1] = fmaf(vb, wv.y, acc[1][q*4+1]);
                acc[1][q*4+2] = fmaf(vb, wv.z, acc[1][q*4+2]);
                acc[1][q*4+3] = fmaf(vb, wv.w, acc[1][q*4+3]);
            }
        }
    }
#pragma unroll
    for (int rr = 0; rr < 2; ++rr) {
        int gr = r0 + rr;
        if (gr >= M) continue;
        float d = dinv[gr];
#pragma unroll
        for (int q = 0; q < CPT / 4; ++q) {
            __half2 p0 = __floats2half2_rn(acc[rr][q*4+0] * d, acc[rr][q*4+1] * d);
            __half2 p1 = __floats2half2_rn(acc[rr][q*4+2] * d, acc[rr][q*4+3] * d);
            half4 hv; hv.lo = p0; hv.hi = p1;
            *(half4*)(Hh + (size_t)gr * NC + c0 + 4 * q) = hv;
        }
    }
}

// out[i,:] = dinv[i] * (Hh[i,:] + sum_{e in row i} Hh[src_e,:]) (+ b)
// thread = (node, 4-feature chunk): one aligned 8B half4 gather per edge,
// fp32 accumulation, float4 store.
template <int NC, bool BIAS>
__global__ void k_agg(const __half* __restrict__ Hh, const int* __restrict__ row_ptr,
                      const int* __restrict__ srcsort, const float* __restrict__ dinv,
                      const float* __restrict__ bias, float* __restrict__ out) {
    constexpr int Q = NC / 4;
    int idx = blockIdx.x * blockDim.x + threadIdx.x;
    if (idx >= NN * Q) return;
    int r = idx / Q, q = idx - r * Q;
    half4 sv = *(const half4*)(Hh + (size_t)r * NC + 4 * q);   // self-loop term
    float2 f0 = __half22float2(sv.lo), f1 = __half22float2(sv.hi);
    float ax = f0.x, ay = f0.y, az = f1.x, aw = f1.y;
    int e0 = row_ptr[r], e1 = row_ptr[r + 1];
    for (int e = e0; e < e1; ++e) {
        int s = srcsort[e];
        half4 v = *(const half4*)(Hh + (size_t)s * NC + 4 * q);
        float2 g0 = __half22float2(v.lo), g1 = __half22float2(v.hi);
        ax += g0.x; ay += g0.y; az += g1.x; aw += g1.y;
    }
    float d = dinv[r];
    ax *= d; ay *= d; az *= d; aw *= d;
    if (BIAS) {
        float4 bv = ((const float4*)bias)[q];
        ax += bv.x; ay += bv.y; az += bv.z; aw += bv.w;
    }
    ((float4*)out)[(size_t)r * Q + q] = make_float4(ax, ay, az, aw);
}

extern "C" void kernel_launch(void* const* d_in, const int* in_sizes, int n_in,
                              void* d_out, int out_size, void* d_ws, size_t ws_size,
                              hipStream_t stream) {
    const float* x  = (const float*)d_in[0];
    const int*   ei = (const int*)d_in[1];   // [2,NE] int32
    const float* W1 = (const float*)d_in[2];
    const float* b1 = (const float*)d_in[3];
    const float* W2 = (const float*)d_in[4];
    const float* b2 = (const float*)d_in[5];
    float* out = (float*)d_out;

    const int* src = ei;
    const int* dst = ei + NE;

    char* p = (char*)d_ws;
    auto take = [&](size_t elems) { void* q = p; p += ((elems * 4 + 255) & ~255ull); return q; };
    int*    bcnt    = (int*)take(NBUCK);
    int*    bbase   = (int*)take(NBUCK + 1);
    int*    gcursor = (int*)take(NBUCK);
    int*    row_ptr = (int*)take(NN + 1);
    float*  dinv    = (float*)take(NN);
    int*    srcsort = (int*)take(NE);
    __half* Hh      = (__half*)take((size_t)NN * 24);  // NN*48 halves
    float*  agg1    = (float*)take((size_t)NN * 48);
    int*    packed  = (int*)agg1;   // alias: packed dead before agg1 is written
    __half* Hh2     = Hh;           // Hh dead after agg1; layer-2 fp16 features

    const int B = 256;
    const int GB = (NN + 127) / 128;   // 782 gemm blocks
    // --- dst-sort of edges ---
    k_zero_b<<<1, 1024, 0, stream>>>(bcnt);
    k_hist<<<PART_G, PART_B, 0, stream>>>(dst, bcnt);
    k_scan<<<1, 1024, 0, stream>>>(bcnt, bbase, gcursor, row_ptr);
    k_part<<<PART_G, PART_B, 0, stream>>>(src, dst, gcursor, packed);
    k_bsort<<<NBUCK, 256, 0, stream>>>(packed, bbase, srcsort, row_ptr, dinv);

    // --- layer 1 ---
    k_gemm<64, 48, 12, false><<<GB, 256, 0, stream>>>(x, W1, nullptr, dinv, Hh, NN);
    k_agg<48, false><<<(NN * 12 + B - 1) / B, B, 0, stream>>>(Hh, row_ptr, srcsort, dinv, nullptr, agg1);

    // --- layer 2 (bias1+relu fused into GEMM input read) ---
    k_gemm<48, 32, 8, true><<<GB, 256, 0, stream>>>(agg1, W2, b1, dinv, Hh2, NN);
    k_agg<32, true><<<(NN * 8 + B - 1) / B, B, 0, stream>>>(Hh2, row_ptr, srcsort, dinv, b2, out);
}

// Round 10
// 235.917 us; speedup vs baseline: 3.5801x; 1.1177x over previous
//
#include <hip/hip_runtime.h>
#include <hip/hip_fp16.h>

// GCN 2-layer. Edges bucket-partitioned by dst, counting-sorted per bucket by
// (dst_local, src_chunk) for L2-friendly monotone gather sweeps. Aggregation
// gathers from an fp16 copy of transformed features (r9: halves random-line
// traffic; FETCH = compulsory 8 XCD x 9.6 MB). r10: 8-way unrolled edge loop
// (8 independent gathers in flight -- r9 was a serial dependent chain at 2.2
// TB/s effective) + full-device preprocessing grids (EPT 32->8).
// r8 lesson: non-contiguous feature slicing explodes line traffic (1.13 GB).
// r5 lesson: transposed-X LDS staging + full unroll => 850 MB scratch spill.
// out = GCNConv(relu(GCNConv(x,W1,b1)), W2, b2); N=100k, E=1.6M, 64->48->32.

#define NN 100000
#define NE 1600000
#define NPB 128                         // nodes per bucket
#define NBUCK ((NN + NPB - 1) / NPB)    // 782
#define PBITS 17                        // src fits in 17 bits
#define PMASK ((1 << PBITS) - 1)
#define CHB 3                           // log2 src chunks
#define CHS 14                          // chunk = src >> 14
#define NKEY (NPB << CHB)               // 1024 sort keys per bucket
#define PART_B 512
#define EPT 8                           // edges per thread (392 blocks: full device)
#define PART_G ((NE + PART_B * EPT - 1) / (PART_B * EPT))   // 391
#define CAP 4096                        // LDS staging per bucket (mean 2048)
#define UN 8                            // agg edge-loop unroll (outstanding gathers)

struct alignas(8) half4 { __half2 lo, hi; };

__global__ void k_zero_b(int* __restrict__ bcnt) {
    int i = threadIdx.x;
    if (i < NBUCK) bcnt[i] = 0;
}

// per-bucket edge histogram (LDS-staged, int atomics only)
__global__ void k_hist(const int* __restrict__ dst, int* __restrict__ bcnt) {
    __shared__ int h[NBUCK];
    for (int i = threadIdx.x; i < NBUCK; i += blockDim.x) h[i] = 0;
    __syncthreads();
    int base = blockIdx.x * (PART_B * EPT);
    for (int k = 0; k < EPT; ++k) {
        int e = base + k * PART_B + threadIdx.x;
        if (e < NE) atomicAdd(&h[dst[e] >> 7], 1);
    }
    __syncthreads();
    for (int i = threadIdx.x; i < NBUCK; i += blockDim.x)
        if (h[i]) atomicAdd(&bcnt[i], h[i]);
}

// single-block exclusive scan over 782 bucket counts; row_ptr[NN] = NE
__global__ void k_scan(const int* __restrict__ bcnt, int* __restrict__ bbase,
                       int* __restrict__ gcursor, int* __restrict__ row_ptr) {
    __shared__ int sm[1024];
    int t = threadIdx.x;
    int v = (t < NBUCK) ? bcnt[t] : 0;
    sm[t] = v; __syncthreads();
    for (int off = 1; off < 1024; off <<= 1) {
        int xv = (t >= off) ? sm[t - off] : 0;
        __syncthreads();
        sm[t] += xv;
        __syncthreads();
    }
    if (t < NBUCK) { int ex = sm[t] - v; bbase[t] = ex; gcursor[t] = ex; }
    if (t == 0) { bbase[NBUCK] = NE; row_ptr[NN] = NE; }
}

// partition edges into bucket order; packed = src | (dst_local << PBITS)
__global__ void k_part(const int* __restrict__ src, const int* __restrict__ dst,
                       int* __restrict__ gcursor, int* __restrict__ packed) {
    __shared__ int h[NBUCK];
    __shared__ int base[NBUCK];
    for (int i = threadIdx.x; i < NBUCK; i += blockDim.x) h[i] = 0;
    __syncthreads();
    int ebase = blockIdx.x * (PART_B * EPT);
    for (int k = 0; k < EPT; ++k) {
        int e = ebase + k * PART_B + threadIdx.x;
        if (e < NE) atomicAdd(&h[dst[e] >> 7], 1);
    }
    __syncthreads();
    for (int i = threadIdx.x; i < NBUCK; i += blockDim.x) {
        int c = h[i];
        if (c) base[i] = atomicAdd(&gcursor[i], c);
        h[i] = 0;
    }
    __syncthreads();
    for (int k = 0; k < EPT; ++k) {
        int e = ebase + k * PART_B + threadIdx.x;
        if (e < NE) {
            int d = dst[e];
            int b = d >> 7;
            int r = atomicAdd(&h[b], 1);
            packed[base[b] + r] = src[e] | ((d & (NPB - 1)) << PBITS);
        }
    }
}

// per-bucket counting sort by (dst_local, src_chunk) -> srcsort, row_ptr, dinv.
__global__ void k_bsort(const int* __restrict__ packed, const int* __restrict__ bbase,
                        int* __restrict__ srcsort, int* __restrict__ row_ptr,
                        float* __restrict__ dinv) {
    __shared__ int stage[CAP];          // 16 KB
    __shared__ int cnt[NKEY];           // 4 KB  (counts -> excl starts -> cursors)
    __shared__ int tsum[256];           // 1 KB
    int tid = threadIdx.x, b = blockIdx.x;
    int e0 = bbase[b], e1 = bbase[b + 1], sz = e1 - e0;
    for (int i = tid; i < NKEY; i += 256) cnt[i] = 0;
    __syncthreads();
    for (int i = tid; i < sz; i += 256) {
        int w = packed[e0 + i];
        if (i < CAP) stage[i] = w;
        int key = ((w >> PBITS) << CHB) | ((w & PMASK) >> CHS);
        atomicAdd(&cnt[key], 1);
    }
    __syncthreads();
    // exclusive scan over NKEY=1024: each thread owns 4 consecutive keys
    int k0 = tid * 4;
    int c0 = cnt[k0], c1 = cnt[k0 + 1], c2 = cnt[k0 + 2], c3 = cnt[k0 + 3];
    int loc = c0 + c1 + c2 + c3;
    tsum[tid] = loc;
    __syncthreads();
    for (int off = 1; off < 256; off <<= 1) {
        int v = (tid >= off) ? tsum[tid - off] : 0;
        __syncthreads();
        tsum[tid] += v;
        __syncthreads();
    }
    int base = tsum[tid] - loc;         // exclusive across threads
    cnt[k0]     = base;
    cnt[k0 + 1] = base + c0;
    cnt[k0 + 2] = base + c0 + c1;
    cnt[k0 + 3] = base + c0 + c1 + c2;
    __syncthreads();
    // row starts / degrees BEFORE cursors get bumped
    if (tid < NPB) {
        int node = b * NPB + tid;
        int rs = cnt[tid << CHB];
        int re = (tid == NPB - 1) ? sz : cnt[(tid + 1) << CHB];
        if (node < NN) {
            row_ptr[node] = e0 + rs;
            dinv[node] = rsqrtf((float)(re - rs + 1));   // +1 self-loop
        }
    }
    __syncthreads();
    for (int i = tid; i < sz; i += 256) {
        int w = (i < CAP) ? stage[i] : packed[e0 + i];
        int key = ((w >> PBITS) << CHB) | ((w & PMASK) >> CHS);
        int p = atomicAdd(&cnt[key], 1);
        srcsort[e0 + p] = w & PMASK;
    }
}

// Register-tiled GEMM: Hh[M,NC] = half( f(X[M,K]) @ W[K,NC] * dinv[row] )
template <int K, int NC, int CPT, bool RELU_IN>
__global__ __launch_bounds__(256) void
k_gemm(const float* __restrict__ X, const float* __restrict__ W,
       const float* __restrict__ bin, const float* __restrict__ dinv,
       __half* __restrict__ Hh, int M) {
    constexpr int CG = NC / CPT;         // 4 col groups
    constexpr int MT = (256 / CG) * 2;   // 128 rows per block
    constexpr int KF4 = K / 4;
    __shared__ float w[K * NC];
    __shared__ float bb[K];
    int tid = threadIdx.x;
    int R0 = blockIdx.x * MT;
    for (int i = tid; i < K * NC; i += 256) w[i] = W[i];
    if (RELU_IN)
        for (int i = tid; i < K; i += 256) bb[i] = bin[i];
    __syncthreads();

    int tc = tid % CG, tr = tid / CG;
    int r0 = R0 + 2 * tr, r1 = r0 + 1;
    int c0 = tc * CPT;
    bool ok0 = r0 < M, ok1 = r1 < M;
    const float4* X4 = (const float4*)X;
    const float4 z4 = make_float4(0.f, 0.f, 0.f, 0.f);

    float acc[2][CPT];
#pragma unroll
    for (int rr = 0; rr < 2; ++rr)
#pragma unroll
        for (int j = 0; j < CPT; ++j) acc[rr][j] = 0.f;

#pragma unroll 2
    for (int k4 = 0; k4 < KF4; ++k4) {
        float4 xa = ok0 ? X4[(size_t)r0 * KF4 + k4] : z4;
        float4 xb = ok1 ? X4[(size_t)r1 * KF4 + k4] : z4;
        float ar[4] = {xa.x, xa.y, xa.z, xa.w};
        float br[4] = {xb.x, xb.y, xb.z, xb.w};
#pragma unroll
        for (int j = 0; j < 4; ++j) {
            float va = ar[j], vb = br[j];
            if (RELU_IN) {
                float bv = bb[4 * k4 + j];
                va = fmaxf(va + bv, 0.f);
                vb = fmaxf(vb + bv, 0.f);
            }
#pragma unroll
            for (int q = 0; q < CPT / 4; ++q) {
                float4 wv = *(const float4*)&w[(4 * k4 + j) * NC + c0 + 4 * q];
                acc[0][q*4+0] = fmaf(va, wv.x, acc[0][q*4+0]);
                acc[0][q*4+1] = fmaf(va, wv.y, acc[0][q*4+1]);
                acc[0][q*4+2] = fmaf(va, wv.z, acc[0][q*4+2]);
                acc[0][q*4+3] = fmaf(va, wv.w, acc[0][q*4+3]);
                acc[1][q*4+0] = fmaf(vb, wv.x, acc[1][q*4+0]);
                acc[1][q*4+1] = fmaf(vb, wv.y, acc[1][q*4+1]);
                acc[1][q*4+2] = fmaf(vb, wv.z, acc[1][q*4+2]);
                acc[1][q*4+3] = fmaf(vb, wv.w, acc[1][q*4+3]);
            }
        }
    }
#pragma unroll
    for (int rr = 0; rr < 2; ++rr) {
        int gr = r0 + rr;
        if (gr >= M) continue;
        float d = dinv[gr];
#pragma unroll
        for (int q = 0; q < CPT / 4; ++q) {
            __half2 p0 = __floats2half2_rn(acc[rr][q*4+0] * d, acc[rr][q*4+1] * d);
            __half2 p1 = __floats2half2_rn(acc[rr][q*4+2] * d, acc[rr][q*4+3] * d);
            half4 hv; hv.lo = p0; hv.hi = p1;
            *(half4*)(Hh + (size_t)gr * NC + c0 + 4 * q) = hv;
        }
    }
}

// out[i,:] = dinv[i] * (Hh[i,:] + sum_{e in row i} Hh[src_e,:]) (+ b)
// thread = (node, 4-feature chunk); UN-way unrolled edge loop keeps UN
// independent 8B gathers in flight (latency hiding); fp32 accumulation.
template <int NC, bool BIAS>
__global__ void k_agg(const __half* __restrict__ Hh, const int* __restrict__ row_ptr,
                      const int* __restrict__ srcsort, const float* __restrict__ dinv,
                      const float* __restrict__ bias, float* __restrict__ out) {
    constexpr int Q = NC / 4;
    int idx = blockIdx.x * blockDim.x + threadIdx.x;
    if (idx >= NN * Q) return;
    int r = idx / Q, q = idx - r * Q;
    half4 sv = *(const half4*)(Hh + (size_t)r * NC + 4 * q);   // self-loop term
    float2 f0 = __half22float2(sv.lo), f1 = __half22float2(sv.hi);
    float ax = f0.x, ay = f0.y, az = f1.x, aw = f1.y;
    int e0 = row_ptr[r], e1 = row_ptr[r + 1];
    int e = e0;
    for (; e + UN <= e1; e += UN) {
        int ss[UN];
#pragma unroll
        for (int u = 0; u < UN; ++u) ss[u] = srcsort[e + u];
        half4 vv[UN];
#pragma unroll
        for (int u = 0; u < UN; ++u)
            vv[u] = *(const half4*)(Hh + (size_t)ss[u] * NC + 4 * q);
#pragma unroll
        for (int u = 0; u < UN; ++u) {
            float2 g0 = __half22float2(vv[u].lo), g1 = __half22float2(vv[u].hi);
            ax += g0.x; ay += g0.y; az += g1.x; aw += g1.y;
        }
    }
    for (; e < e1; ++e) {
        int s = srcsort[e];
        half4 v = *(const half4*)(Hh + (size_t)s * NC + 4 * q);
        float2 g0 = __half22float2(v.lo), g1 = __half22float2(v.hi);
        ax += g0.x; ay += g0.y; az += g1.x; aw += g1.y;
    }
    float d = dinv[r];
    ax *= d; ay *= d; az *= d; aw *= d;
    if (BIAS) {
        float4 bv = ((const float4*)bias)[q];
        ax += bv.x; ay += bv.y; az += bv.z; aw += bv.w;
    }
    ((float4*)out)[(size_t)r * Q + q] = make_float4(ax, ay, az, aw);
}

extern "C" void kernel_launch(void* const* d_in, const int* in_sizes, int n_in,
                              void* d_out, int out_size, void* d_ws, size_t ws_size,
                              hipStream_t stream) {
    const float* x  = (const float*)d_in[0];
    const int*   ei = (const int*)d_in[1];   // [2,NE] int32
    const float* W1 = (const float*)d_in[2];
    const float* b1 = (const float*)d_in[3];
    const float* W2 = (const float*)d_in[4];
    const float* b2 = (const float*)d_in[5];
    float* out = (float*)d_out;

    const int* src = ei;
    const int* dst = ei + NE;

    char* p = (char*)d_ws;
    auto take = [&](size_t elems) { void* q = p; p += ((elems * 4 + 255) & ~255ull); return q; };
    int*    bcnt    = (int*)take(NBUCK);
    int*    bbase   = (int*)take(NBUCK + 1);
    int*    gcursor = (int*)take(NBUCK);
    int*    row_ptr = (int*)take(NN + 1);
    float*  dinv    = (float*)take(NN);
    int*    srcsort = (int*)take(NE);
    __half* Hh      = (__half*)take((size_t)NN * 24);  // NN*48 halves
    float*  agg1    = (float*)take((size_t)NN * 48);
    int*    packed  = (int*)agg1;   // alias: packed dead before agg1 is written
    __half* Hh2     = Hh;           // Hh dead after agg1; layer-2 fp16 features

    const int B = 256;
    const int GB = (NN + 127) / 128;   // 782 gemm blocks
    // --- dst-sort of edges ---
    k_zero_b<<<1, 1024, 0, stream>>>(bcnt);
    k_hist<<<PART_G, PART_B, 0, stream>>>(dst, bcnt);
    k_scan<<<1, 1024, 0, stream>>>(bcnt, bbase, gcursor, row_ptr);
    k_part<<<PART_G, PART_B, 0, stream>>>(src, dst, gcursor, packed);
    k_bsort<<<NBUCK, 256, 0, stream>>>(packed, bbase, srcsort, row_ptr, dinv);

    // --- layer 1 ---
    k_gemm<64, 48, 12, false><<<GB, 256, 0, stream>>>(x, W1, nullptr, dinv, Hh, NN);
    k_agg<48, false><<<(NN * 12 + B - 1) / B, B, 0, stream>>>(Hh, row_ptr, srcsort, dinv, nullptr, agg1);

    // --- layer 2 (bias1+relu fused into GEMM input read) ---
    k_gemm<48, 32, 8, true><<<GB, 256, 0, stream>>>(agg1, W2, b1, dinv, Hh2, NN);
    k_agg<32, true><<<(NN * 8 + B - 1) / B, B, 0, stream>>>(Hh2, row_ptr, srcsort, dinv, b2, out);
}

// Round 11
// 235.659 us; speedup vs baseline: 3.5840x; 1.0011x over previous
//
#include <hip/hip_runtime.h>
#include <hip/hip_fp16.h>

// GCN 2-layer. Edges bucket-partitioned by dst, counting-sorted per bucket by
// (dst_local, src_chunk) for L2-friendly monotone gather sweeps. Aggregation
// gathers 16B half8 rows-chunks from an fp16 feature copy (r9: halves random-
// line traffic; r10: 8-way unroll for MLP; r11: 16B gathers halve load-instr
// count -- agg was vmem-issue bound at 2.2 TB/s effective, bytes compulsory).
// r8 lesson: non-contiguous feature slicing explodes line traffic (1.13 GB).
// r5 lesson: transposed-X LDS staging + full unroll => 850 MB scratch spill.
// out = GCNConv(relu(GCNConv(x,W1,b1)), W2, b2); N=100k, E=1.6M, 64->48->32.

#define NN 100000
#define NE 1600000
#define NPB 128                         // nodes per bucket
#define NBUCK ((NN + NPB - 1) / NPB)    // 782
#define PBITS 17                        // src fits in 17 bits
#define PMASK ((1 << PBITS) - 1)
#define CHB 3                           // log2 src chunks
#define CHS 14                          // chunk = src >> 14
#define NKEY (NPB << CHB)               // 1024 sort keys per bucket
#define PART_B 512
#define EPT 8                           // edges per thread (391 blocks: full device)
#define PART_G ((NE + PART_B * EPT - 1) / (PART_B * EPT))   // 391
#define CAP 4096                        // LDS staging per bucket (mean 2048)
#define UN 8                            // agg edge-loop unroll (outstanding gathers)

struct alignas(8)  half4 { __half2 lo, hi; };
struct alignas(16) half8 { __half2 a, b, c, d; };

__global__ void k_zero_b(int* __restrict__ bcnt) {
    int i = threadIdx.x;
    if (i < NBUCK) bcnt[i] = 0;
}

// per-bucket edge histogram (LDS-staged, int atomics only)
__global__ void k_hist(const int* __restrict__ dst, int* __restrict__ bcnt) {
    __shared__ int h[NBUCK];
    for (int i = threadIdx.x; i < NBUCK; i += blockDim.x) h[i] = 0;
    __syncthreads();
    int base = blockIdx.x * (PART_B * EPT);
    for (int k = 0; k < EPT; ++k) {
        int e = base + k * PART_B + threadIdx.x;
        if (e < NE) atomicAdd(&h[dst[e] >> 7], 1);
    }
    __syncthreads();
    for (int i = threadIdx.x; i < NBUCK; i += blockDim.x)
        if (h[i]) atomicAdd(&bcnt[i], h[i]);
}

// single-block exclusive scan over 782 bucket counts; row_ptr[NN] = NE
__global__ void k_scan(const int* __restrict__ bcnt, int* __restrict__ bbase,
                       int* __restrict__ gcursor, int* __restrict__ row_ptr) {
    __shared__ int sm[1024];
    int t = threadIdx.x;
    int v = (t < NBUCK) ? bcnt[t] : 0;
    sm[t] = v; __syncthreads();
    for (int off = 1; off < 1024; off <<= 1) {
        int xv = (t >= off) ? sm[t - off] : 0;
        __syncthreads();
        sm[t] += xv;
        __syncthreads();
    }
    if (t < NBUCK) { int ex = sm[t] - v; bbase[t] = ex; gcursor[t] = ex; }
    if (t == 0) { bbase[NBUCK] = NE; row_ptr[NN] = NE; }
}

// partition edges into bucket order; packed = src | (dst_local << PBITS)
__global__ void k_part(const int* __restrict__ src, const int* __restrict__ dst,
                       int* __restrict__ gcursor, int* __restrict__ packed) {
    __shared__ int h[NBUCK];
    __shared__ int base[NBUCK];
    for (int i = threadIdx.x; i < NBUCK; i += blockDim.x) h[i] = 0;
    __syncthreads();
    int ebase = blockIdx.x * (PART_B * EPT);
    for (int k = 0; k < EPT; ++k) {
        int e = ebase + k * PART_B + threadIdx.x;
        if (e < NE) atomicAdd(&h[dst[e] >> 7], 1);
    }
    __syncthreads();
    for (int i = threadIdx.x; i < NBUCK; i += blockDim.x) {
        int c = h[i];
        if (c) base[i] = atomicAdd(&gcursor[i], c);
        h[i] = 0;
    }
    __syncthreads();
    for (int k = 0; k < EPT; ++k) {
        int e = ebase + k * PART_B + threadIdx.x;
        if (e < NE) {
            int d = dst[e];
            int b = d >> 7;
            int r = atomicAdd(&h[b], 1);
            packed[base[b] + r] = src[e] | ((d & (NPB - 1)) << PBITS);
        }
    }
}

// per-bucket counting sort by (dst_local, src_chunk) -> srcsort, row_ptr, dinv.
__global__ void k_bsort(const int* __restrict__ packed, const int* __restrict__ bbase,
                        int* __restrict__ srcsort, int* __restrict__ row_ptr,
                        float* __restrict__ dinv) {
    __shared__ int stage[CAP];          // 16 KB
    __shared__ int cnt[NKEY];           // 4 KB  (counts -> excl starts -> cursors)
    __shared__ int tsum[256];           // 1 KB
    int tid = threadIdx.x, b = blockIdx.x;
    int e0 = bbase[b], e1 = bbase[b + 1], sz = e1 - e0;
    for (int i = tid; i < NKEY; i += 256) cnt[i] = 0;
    __syncthreads();
    for (int i = tid; i < sz; i += 256) {
        int w = packed[e0 + i];
        if (i < CAP) stage[i] = w;
        int key = ((w >> PBITS) << CHB) | ((w & PMASK) >> CHS);
        atomicAdd(&cnt[key], 1);
    }
    __syncthreads();
    // exclusive scan over NKEY=1024: each thread owns 4 consecutive keys
    int k0 = tid * 4;
    int c0 = cnt[k0], c1 = cnt[k0 + 1], c2 = cnt[k0 + 2], c3 = cnt[k0 + 3];
    int loc = c0 + c1 + c2 + c3;
    tsum[tid] = loc;
    __syncthreads();
    for (int off = 1; off < 256; off <<= 1) {
        int v = (tid >= off) ? tsum[tid - off] : 0;
        __syncthreads();
        tsum[tid] += v;
        __syncthreads();
    }
    int base = tsum[tid] - loc;         // exclusive across threads
    cnt[k0]     = base;
    cnt[k0 + 1] = base + c0;
    cnt[k0 + 2] = base + c0 + c1;
    cnt[k0 + 3] = base + c0 + c1 + c2;
    __syncthreads();
    // row starts / degrees BEFORE cursors get bumped
    if (tid < NPB) {
        int node = b * NPB + tid;
        int rs = cnt[tid << CHB];
        int re = (tid == NPB - 1) ? sz : cnt[(tid + 1) << CHB];
        if (node < NN) {
            row_ptr[node] = e0 + rs;
            dinv[node] = rsqrtf((float)(re - rs + 1));   // +1 self-loop
        }
    }
    __syncthreads();
    for (int i = tid; i < sz; i += 256) {
        int w = (i < CAP) ? stage[i] : packed[e0 + i];
        int key = ((w >> PBITS) << CHB) | ((w & PMASK) >> CHS);
        int p = atomicAdd(&cnt[key], 1);
        srcsort[e0 + p] = w & PMASK;
    }
}

// Register-tiled GEMM: Hh[M,NC] = half( f(X[M,K]) @ W[K,NC] * dinv[row] )
template <int K, int NC, int CPT, bool RELU_IN>
__global__ __launch_bounds__(256) void
k_gemm(const float* __restrict__ X, const float* __restrict__ W,
       const float* __restrict__ bin, const float* __restrict__ dinv,
       __half* __restrict__ Hh, int M) {
    constexpr int CG = NC / CPT;         // 4 col groups
    constexpr int MT = (256 / CG) * 2;   // 128 rows per block
    constexpr int KF4 = K / 4;
    __shared__ float w[K * NC];
    __shared__ float bb[K];
    int tid = threadIdx.x;
    int R0 = blockIdx.x * MT;
    for (int i = tid; i < K * NC; i += 256) w[i] = W[i];
    if (RELU_IN)
        for (int i = tid; i < K; i += 256) bb[i] = bin[i];
    __syncthreads();

    int tc = tid % CG, tr = tid / CG;
    int r0 = R0 + 2 * tr, r1 = r0 + 1;
    int c0 = tc * CPT;
    bool ok0 = r0 < M, ok1 = r1 < M;
    const float4* X4 = (const float4*)X;
    const float4 z4 = make_float4(0.f, 0.f, 0.f, 0.f);

    float acc[2][CPT];
#pragma unroll
    for (int rr = 0; rr < 2; ++rr)
#pragma unroll
        for (int j = 0; j < CPT; ++j) acc[rr][j] = 0.f;

#pragma unroll 2
    for (int k4 = 0; k4 < KF4; ++k4) {
        float4 xa = ok0 ? X4[(size_t)r0 * KF4 + k4] : z4;
        float4 xb = ok1 ? X4[(size_t)r1 * KF4 + k4] : z4;
        float ar[4] = {xa.x, xa.y, xa.z, xa.w};
        float br[4] = {xb.x, xb.y, xb.z, xb.w};
#pragma unroll
        for (int j = 0; j < 4; ++j) {
            float va = ar[j], vb = br[j];
            if (RELU_IN) {
                float bv = bb[4 * k4 + j];
                va = fmaxf(va + bv, 0.f);
                vb = fmaxf(vb + bv, 0.f);
            }
#pragma unroll
            for (int q = 0; q < CPT / 4; ++q) {
                float4 wv = *(const float4*)&w[(4 * k4 + j) * NC + c0 + 4 * q];
                acc[0][q*4+0] = fmaf(va, wv.x, acc[0][q*4+0]);
                acc[0][q*4+1] = fmaf(va, wv.y, acc[0][q*4+1]);
                acc[0][q*4+2] = fmaf(va, wv.z, acc[0][q*4+2]);
                acc[0][q*4+3] = fmaf(va, wv.w, acc[0][q*4+3]);
                acc[1][q*4+0] = fmaf(vb, wv.x, acc[1][q*4+0]);
                acc[1][q*4+1] = fmaf(vb, wv.y, acc[1][q*4+1]);
                acc[1][q*4+2] = fmaf(vb, wv.z, acc[1][q*4+2]);
                acc[1][q*4+3] = fmaf(vb, wv.w, acc[1][q*4+3]);
            }
        }
    }
#pragma unroll
    for (int rr = 0; rr < 2; ++rr) {
        int gr = r0 + rr;
        if (gr >= M) continue;
        float d = dinv[gr];
#pragma unroll
        for (int q = 0; q < CPT / 4; ++q) {
            __half2 p0 = __floats2half2_rn(acc[rr][q*4+0] * d, acc[rr][q*4+1] * d);
            __half2 p1 = __floats2half2_rn(acc[rr][q*4+2] * d, acc[rr][q*4+3] * d);
            half4 hv; hv.lo = p0; hv.hi = p1;
            *(half4*)(Hh + (size_t)gr * NC + c0 + 4 * q) = hv;
        }
    }
}

// out[i,:] = dinv[i] * (Hh[i,:] + sum_{e in row i} Hh[src_e,:]) (+ b)
// thread = (node, 8-feature/16B chunk); UN-way unrolled edge loop keeps UN
// independent 16B gathers in flight; fp32 accumulation; 2x float4 stores.
template <int NC, bool BIAS>
__global__ void k_agg(const __half* __restrict__ Hh, const int* __restrict__ row_ptr,
                      const int* __restrict__ srcsort, const float* __restrict__ dinv,
                      const float* __restrict__ bias, float* __restrict__ out) {
    constexpr int Q = NC / 8;
    int idx = blockIdx.x * blockDim.x + threadIdx.x;
    if (idx >= NN * Q) return;
    int r = idx / Q, q = idx - r * Q;
    half8 sv = *(const half8*)(Hh + (size_t)r * NC + 8 * q);   // self-loop term
    float2 f0 = __half22float2(sv.a), f1 = __half22float2(sv.b);
    float2 f2 = __half22float2(sv.c), f3 = __half22float2(sv.d);
    float a0 = f0.x, a1 = f0.y, a2 = f1.x, a3 = f1.y;
    float a4 = f2.x, a5 = f2.y, a6 = f3.x, a7 = f3.y;
    int e0 = row_ptr[r], e1 = row_ptr[r + 1];
    int e = e0;
    for (; e + UN <= e1; e += UN) {
        int ss[UN];
#pragma unroll
        for (int u = 0; u < UN; ++u) ss[u] = srcsort[e + u];
        half8 vv[UN];
#pragma unroll
        for (int u = 0; u < UN; ++u)
            vv[u] = *(const half8*)(Hh + (size_t)ss[u] * NC + 8 * q);
#pragma unroll
        for (int u = 0; u < UN; ++u) {
            float2 g0 = __half22float2(vv[u].a), g1 = __half22float2(vv[u].b);
            float2 g2 = __half22float2(vv[u].c), g3 = __half22float2(vv[u].d);
            a0 += g0.x; a1 += g0.y; a2 += g1.x; a3 += g1.y;
            a4 += g2.x; a5 += g2.y; a6 += g3.x; a7 += g3.y;
        }
    }
    for (; e < e1; ++e) {
        int s = srcsort[e];
        half8 v = *(const half8*)(Hh + (size_t)s * NC + 8 * q);
        float2 g0 = __half22float2(v.a), g1 = __half22float2(v.b);
        float2 g2 = __half22float2(v.c), g3 = __half22float2(v.d);
        a0 += g0.x; a1 += g0.y; a2 += g1.x; a3 += g1.y;
        a4 += g2.x; a5 += g2.y; a6 += g3.x; a7 += g3.y;
    }
    float d = dinv[r];
    a0 *= d; a1 *= d; a2 *= d; a3 *= d; a4 *= d; a5 *= d; a6 *= d; a7 *= d;
    if (BIAS) {
        const float4* b4 = (const float4*)bias;
        float4 bv0 = b4[2 * q], bv1 = b4[2 * q + 1];
        a0 += bv0.x; a1 += bv0.y; a2 += bv0.z; a3 += bv0.w;
        a4 += bv1.x; a5 += bv1.y; a6 += bv1.z; a7 += bv1.w;
    }
    float4* o4 = (float4*)(out + (size_t)r * NC + 8 * q);
    o4[0] = make_float4(a0, a1, a2, a3);
    o4[1] = make_float4(a4, a5, a6, a7);
}

extern "C" void kernel_launch(void* const* d_in, const int* in_sizes, int n_in,
                              void* d_out, int out_size, void* d_ws, size_t ws_size,
                              hipStream_t stream) {
    const float* x  = (const float*)d_in[0];
    const int*   ei = (const int*)d_in[1];   // [2,NE] int32
    const float* W1 = (const float*)d_in[2];
    const float* b1 = (const float*)d_in[3];
    const float* W2 = (const float*)d_in[4];
    const float* b2 = (const float*)d_in[5];
    float* out = (float*)d_out;

    const int* src = ei;
    const int* dst = ei + NE;

    char* p = (char*)d_ws;
    auto take = [&](size_t elems) { void* q = p; p += ((elems * 4 + 255) & ~255ull); return q; };
    int*    bcnt    = (int*)take(NBUCK);
    int*    bbase   = (int*)take(NBUCK + 1);
    int*    gcursor = (int*)take(NBUCK);
    int*    row_ptr = (int*)take(NN + 1);
    float*  dinv    = (float*)take(NN);
    int*    srcsort = (int*)take(NE);
    __half* Hh      = (__half*)take((size_t)NN * 24);  // NN*48 halves
    float*  agg1    = (float*)take((size_t)NN * 48);
    int*    packed  = (int*)agg1;   // alias: packed dead before agg1 is written
    __half* Hh2     = Hh;           // Hh dead after agg1; layer-2 fp16 features

    const int B = 256;
    const int GB = (NN + 127) / 128;   // 782 gemm blocks
    // --- dst-sort of edges ---
    k_zero_b<<<1, 1024, 0, stream>>>(bcnt);
    k_hist<<<PART_G, PART_B, 0, stream>>>(dst, bcnt);
    k_scan<<<1, 1024, 0, stream>>>(bcnt, bbase, gcursor, row_ptr);
    k_part<<<PART_G, PART_B, 0, stream>>>(src, dst, gcursor, packed);
    k_bsort<<<NBUCK, 256, 0, stream>>>(packed, bbase, srcsort, row_ptr, dinv);

    // --- layer 1 ---
    k_gemm<64, 48, 12, false><<<GB, 256, 0, stream>>>(x, W1, nullptr, dinv, Hh, NN);
    k_agg<48, false><<<(NN * 6 + B - 1) / B, B, 0, stream>>>(Hh, row_ptr, srcsort, dinv, nullptr, agg1);

    // --- layer 2 (bias1+relu fused into GEMM input read) ---
    k_gemm<48, 32, 8, true><<<GB, 256, 0, stream>>>(agg1, W2, b1, dinv, Hh2, NN);
    k_agg<32, true><<<(NN * 4 + B - 1) / B, B, 0, stream>>>(Hh2, row_ptr, srcsort, dinv, b2, out);
}

// Round 12
// 222.581 us; speedup vs baseline: 3.7946x; 1.0588x over previous
//
#include <hip/hip_runtime.h>
#include <hip/hip_fp16.h>

// GCN 2-layer. Edges bucket-partitioned by dst, counting-sorted per bucket by
// (dst_local, src_chunk) for L2-friendly monotone gather sweeps. Aggregation
// gathers 16B half8 chunks from an fp16 feature copy (r9). r12: GEMM2 fused
// into layer-1 aggregation via an LDS row tile (saves the 38 MB agg1 round
// trip + one dispatch; agg proved random-line-ceiling bound in r9-r11, so
// reduce passes, not gather width). Hh2 gets its own buffer (aliasing Hh
// would race: blocks write layer-2 rows while others still gather layer-1).
// r11 lesson: 16B vs 8B gathers neutral -- agg is L2-miss/fabric bound.
// r8 lesson: non-contiguous feature slicing explodes line traffic (1.13 GB).
// r5 lesson: transposed-X LDS staging + full unroll => 850 MB scratch spill.
// out = GCNConv(relu(GCNConv(x,W1,b1)), W2, b2); N=100k, E=1.6M, 64->48->32.

#define NN 100000
#define NE 1600000
#define NPB 128                         // nodes per bucket
#define NBUCK ((NN + NPB - 1) / NPB)    // 782
#define PBITS 17                        // src fits in 17 bits
#define PMASK ((1 << PBITS) - 1)
#define CHB 3                           // log2 src chunks
#define CHS 14                          // chunk = src >> 14
#define NKEY (NPB << CHB)               // 1024 sort keys per bucket
#define PART_B 512
#define EPT 8                           // edges per thread (391 blocks)
#define PART_G ((NE + PART_B * EPT - 1) / (PART_B * EPT))   // 391
#define CAP 4096                        // LDS staging per bucket (mean 2048)
#define UN 8                            // agg edge-loop unroll

struct alignas(8)  half4 { __half2 lo, hi; };
struct alignas(16) half8 { __half2 a, b, c, d; };

__global__ void k_zero_b(int* __restrict__ bcnt) {
    int i = threadIdx.x;
    if (i < NBUCK) bcnt[i] = 0;
}

__global__ void k_hist(const int* __restrict__ dst, int* __restrict__ bcnt) {
    __shared__ int h[NBUCK];
    for (int i = threadIdx.x; i < NBUCK; i += blockDim.x) h[i] = 0;
    __syncthreads();
    int base = blockIdx.x * (PART_B * EPT);
    for (int k = 0; k < EPT; ++k) {
        int e = base + k * PART_B + threadIdx.x;
        if (e < NE) atomicAdd(&h[dst[e] >> 7], 1);
    }
    __syncthreads();
    for (int i = threadIdx.x; i < NBUCK; i += blockDim.x)
        if (h[i]) atomicAdd(&bcnt[i], h[i]);
}

__global__ void k_scan(const int* __restrict__ bcnt, int* __restrict__ bbase,
                       int* __restrict__ gcursor, int* __restrict__ row_ptr) {
    __shared__ int sm[1024];
    int t = threadIdx.x;
    int v = (t < NBUCK) ? bcnt[t] : 0;
    sm[t] = v; __syncthreads();
    for (int off = 1; off < 1024; off <<= 1) {
        int xv = (t >= off) ? sm[t - off] : 0;
        __syncthreads();
        sm[t] += xv;
        __syncthreads();
    }
    if (t < NBUCK) { int ex = sm[t] - v; bbase[t] = ex; gcursor[t] = ex; }
    if (t == 0) { bbase[NBUCK] = NE; row_ptr[NN] = NE; }
}

__global__ void k_part(const int* __restrict__ src, const int* __restrict__ dst,
                       int* __restrict__ gcursor, int* __restrict__ packed) {
    __shared__ int h[NBUCK];
    __shared__ int base[NBUCK];
    for (int i = threadIdx.x; i < NBUCK; i += blockDim.x) h[i] = 0;
    __syncthreads();
    int ebase = blockIdx.x * (PART_B * EPT);
    for (int k = 0; k < EPT; ++k) {
        int e = ebase + k * PART_B + threadIdx.x;
        if (e < NE) atomicAdd(&h[dst[e] >> 7], 1);
    }
    __syncthreads();
    for (int i = threadIdx.x; i < NBUCK; i += blockDim.x) {
        int c = h[i];
        if (c) base[i] = atomicAdd(&gcursor[i], c);
        h[i] = 0;
    }
    __syncthreads();
    for (int k = 0; k < EPT; ++k) {
        int e = ebase + k * PART_B + threadIdx.x;
        if (e < NE) {
            int d = dst[e];
            int b = d >> 7;
            int r = atomicAdd(&h[b], 1);
            packed[base[b] + r] = src[e] | ((d & (NPB - 1)) << PBITS);
        }
    }
}

__global__ void k_bsort(const int* __restrict__ packed, const int* __restrict__ bbase,
                        int* __restrict__ srcsort, int* __restrict__ row_ptr,
                        float* __restrict__ dinv) {
    __shared__ int stage[CAP];
    __shared__ int cnt[NKEY];
    __shared__ int tsum[256];
    int tid = threadIdx.x, b = blockIdx.x;
    int e0 = bbase[b], e1 = bbase[b + 1], sz = e1 - e0;
    for (int i = tid; i < NKEY; i += 256) cnt[i] = 0;
    __syncthreads();
    for (int i = tid; i < sz; i += 256) {
        int w = packed[e0 + i];
        if (i < CAP) stage[i] = w;
        int key = ((w >> PBITS) << CHB) | ((w & PMASK) >> CHS);
        atomicAdd(&cnt[key], 1);
    }
    __syncthreads();
    int k0 = tid * 4;
    int c0 = cnt[k0], c1 = cnt[k0 + 1], c2 = cnt[k0 + 2], c3 = cnt[k0 + 3];
    int loc = c0 + c1 + c2 + c3;
    tsum[tid] = loc;
    __syncthreads();
    for (int off = 1; off < 256; off <<= 1) {
        int v = (tid >= off) ? tsum[tid - off] : 0;
        __syncthreads();
        tsum[tid] += v;
        __syncthreads();
    }
    int base = tsum[tid] - loc;
    cnt[k0]     = base;
    cnt[k0 + 1] = base + c0;
    cnt[k0 + 2] = base + c0 + c1;
    cnt[k0 + 3] = base + c0 + c1 + c2;
    __syncthreads();
    if (tid < NPB) {
        int node = b * NPB + tid;
        int rs = cnt[tid << CHB];
        int re = (tid == NPB - 1) ? sz : cnt[(tid + 1) << CHB];
        if (node < NN) {
            row_ptr[node] = e0 + rs;
            dinv[node] = rsqrtf((float)(re - rs + 1));   // +1 self-loop
        }
    }
    __syncthreads();
    for (int i = tid; i < sz; i += 256) {
        int w = (i < CAP) ? stage[i] : packed[e0 + i];
        int key = ((w >> PBITS) << CHB) | ((w & PMASK) >> CHS);
        int p = atomicAdd(&cnt[key], 1);
        srcsort[e0 + p] = w & PMASK;
    }
}

// Register-tiled GEMM1: Hh[M,48] = half( X[M,64] @ W1 * dinv[row] )
template <int K, int NC, int CPT>
__global__ __launch_bounds__(256) void
k_gemm(const float* __restrict__ X, const float* __restrict__ W,
       const float* __restrict__ dinv, __half* __restrict__ Hh, int M) {
    constexpr int CG = NC / CPT;
    constexpr int MT = (256 / CG) * 2;   // 128 rows per block
    constexpr int KF4 = K / 4;
    __shared__ float w[K * NC];
    int tid = threadIdx.x;
    int R0 = blockIdx.x * MT;
    for (int i = tid; i < K * NC; i += 256) w[i] = W[i];
    __syncthreads();

    int tc = tid % CG, tr = tid / CG;
    int r0 = R0 + 2 * tr, r1 = r0 + 1;
    int c0 = tc * CPT;
    bool ok0 = r0 < M, ok1 = r1 < M;
    const float4* X4 = (const float4*)X;
    const float4 z4 = make_float4(0.f, 0.f, 0.f, 0.f);

    float acc[2][CPT];
#pragma unroll
    for (int rr = 0; rr < 2; ++rr)
#pragma unroll
        for (int j = 0; j < CPT; ++j) acc[rr][j] = 0.f;

#pragma unroll 2
    for (int k4 = 0; k4 < KF4; ++k4) {
        float4 xa = ok0 ? X4[(size_t)r0 * KF4 + k4] : z4;
        float4 xb = ok1 ? X4[(size_t)r1 * KF4 + k4] : z4;
        float ar[4] = {xa.x, xa.y, xa.z, xa.w};
        float br[4] = {xb.x, xb.y, xb.z, xb.w};
#pragma unroll
        for (int j = 0; j < 4; ++j) {
            float va = ar[j], vb = br[j];
#pragma unroll
            for (int q = 0; q < CPT / 4; ++q) {
                float4 wv = *(const float4*)&w[(4 * k4 + j) * NC + c0 + 4 * q];
                acc[0][q*4+0] = fmaf(va, wv.x, acc[0][q*4+0]);
                acc[0][q*4+1] = fmaf(va, wv.y, acc[0][q*4+1]);
                acc[0][q*4+2] = fmaf(va, wv.z, acc[0][q*4+2]);
                acc[0][q*4+3] = fmaf(va, wv.w, acc[0][q*4+3]);
                acc[1][q*4+0] = fmaf(vb, wv.x, acc[1][q*4+0]);
                acc[1][q*4+1] = fmaf(vb, wv.y, acc[1][q*4+1]);
                acc[1][q*4+2] = fmaf(vb, wv.z, acc[1][q*4+2]);
                acc[1][q*4+3] = fmaf(vb, wv.w, acc[1][q*4+3]);
            }
        }
    }
#pragma unroll
    for (int rr = 0; rr < 2; ++rr) {
        int gr = r0 + rr;
        if (gr >= M) continue;
        float d = dinv[gr];
#pragma unroll
        for (int q = 0; q < CPT / 4; ++q) {
            __half2 p0 = __floats2half2_rn(acc[rr][q*4+0] * d, acc[rr][q*4+1] * d);
            __half2 p1 = __floats2half2_rn(acc[rr][q*4+2] * d, acc[rr][q*4+3] * d);
            half4 hv; hv.lo = p0; hv.hi = p1;
            *(half4*)(Hh + (size_t)gr * NC + c0 + 4 * q) = hv;
        }
    }
}

// Fused layer-1 aggregation + relu/b1 + GEMM2 + dinv scaling.
// Phase 1: block aggregates 128 rows x 48 feats into LDS Xs (padded stride 49),
//          Xs = relu(dinv*(self + sum_neighbors) + b1).
// Phase 2: register-tiled matvec (2 rows x 8 cols/thread) with W2 from LDS;
//          Hh2[r,:32] = half((Xs[r,:] @ W2) * dinv[r]).
__global__ __launch_bounds__(256) void
k_fused48(const __half* __restrict__ Hh, const int* __restrict__ row_ptr,
          const int* __restrict__ srcsort, const float* __restrict__ dinv,
          const float* __restrict__ b1, const float* __restrict__ W2,
          __half* __restrict__ Hh2) {
    constexpr int ROWS = 128, XS = 49;
    __shared__ float Xs[ROWS * XS];      // 25088 B
    __shared__ float w2[48 * 32];        // 6144 B
    __shared__ float bb[48];
    int tid = threadIdx.x;
    int R0 = blockIdx.x * ROWS;
    for (int i = tid; i < 48 * 32; i += 256) w2[i] = W2[i];
    if (tid < 48) bb[tid] = b1[tid];
    __syncthreads();

    // ---- phase 1: aggregate into Xs ----
    for (int t = tid; t < ROWS * 6; t += 256) {
        int lr = t / 6, q = t - lr * 6;
        int r = R0 + lr;
        if (r >= NN) continue;
        half8 sv = *(const half8*)(Hh + (size_t)r * 48 + 8 * q);   // self-loop
        float2 f0 = __half22float2(sv.a), f1 = __half22float2(sv.b);
        float2 f2 = __half22float2(sv.c), f3 = __half22float2(sv.d);
        float a0 = f0.x, a1 = f0.y, a2 = f1.x, a3 = f1.y;
        float a4 = f2.x, a5 = f2.y, a6 = f3.x, a7 = f3.y;
        int e0 = row_ptr[r], e1 = row_ptr[r + 1];
        int e = e0;
        for (; e + UN <= e1; e += UN) {
            int ss[UN];
#pragma unroll
            for (int u = 0; u < UN; ++u) ss[u] = srcsort[e + u];
            half8 vv[UN];
#pragma unroll
            for (int u = 0; u < UN; ++u)
                vv[u] = *(const half8*)(Hh + (size_t)ss[u] * 48 + 8 * q);
#pragma unroll
            for (int u = 0; u < UN; ++u) {
                float2 g0 = __half22float2(vv[u].a), g1 = __half22float2(vv[u].b);
                float2 g2 = __half22float2(vv[u].c), g3 = __half22float2(vv[u].d);
                a0 += g0.x; a1 += g0.y; a2 += g1.x; a3 += g1.y;
                a4 += g2.x; a5 += g2.y; a6 += g3.x; a7 += g3.y;
            }
        }
        for (; e < e1; ++e) {
            int s = srcsort[e];
            half8 v = *(const half8*)(Hh + (size_t)s * 48 + 8 * q);
            float2 g0 = __half22float2(v.a), g1 = __half22float2(v.b);
            float2 g2 = __half22float2(v.c), g3 = __half22float2(v.d);
            a0 += g0.x; a1 += g0.y; a2 += g1.x; a3 += g1.y;
            a4 += g2.x; a5 += g2.y; a6 += g3.x; a7 += g3.y;
        }
        float d = dinv[r];
        float* xr = &Xs[lr * XS + 8 * q];
        const float* bf = &bb[8 * q];
        xr[0] = fmaxf(fmaf(a0, d, bf[0]), 0.f);
        xr[1] = fmaxf(fmaf(a1, d, bf[1]), 0.f);
        xr[2] = fmaxf(fmaf(a2, d, bf[2]), 0.f);
        xr[3] = fmaxf(fmaf(a3, d, bf[3]), 0.f);
        xr[4] = fmaxf(fmaf(a4, d, bf[4]), 0.f);
        xr[5] = fmaxf(fmaf(a5, d, bf[5]), 0.f);
        xr[6] = fmaxf(fmaf(a6, d, bf[6]), 0.f);
        xr[7] = fmaxf(fmaf(a7, d, bf[7]), 0.f);
    }
    __syncthreads();

    // ---- phase 2: Xs[128,48] @ W2[48,32] -> Hh2 (fp16) ----
    int tc = tid & 3, tr = tid >> 2;     // 4 col groups x 64 row-pairs
    int r0l = 2 * tr, c0 = tc * 8;
    float acc[2][8];
#pragma unroll
    for (int rr = 0; rr < 2; ++rr)
#pragma unroll
        for (int j = 0; j < 8; ++j) acc[rr][j] = 0.f;
#pragma unroll 4
    for (int k = 0; k < 48; ++k) {
        float x0 = Xs[r0l * XS + k];
        float x1 = Xs[(r0l + 1) * XS + k];
        float4 wv0 = *(const float4*)&w2[k * 32 + c0];
        float4 wv1 = *(const float4*)&w2[k * 32 + c0 + 4];
        acc[0][0] = fmaf(x0, wv0.x, acc[0][0]); acc[0][1] = fmaf(x0, wv0.y, acc[0][1]);
        acc[0][2] = fmaf(x0, wv0.z, acc[0][2]); acc[0][3] = fmaf(x0, wv0.w, acc[0][3]);
        acc[0][4] = fmaf(x0, wv1.x, acc[0][4]); acc[0][5] = fmaf(x0, wv1.y, acc[0][5]);
        acc[0][6] = fmaf(x0, wv1.z, acc[0][6]); acc[0][7] = fmaf(x0, wv1.w, acc[0][7]);
        acc[1][0] = fmaf(x1, wv0.x, acc[1][0]); acc[1][1] = fmaf(x1, wv0.y, acc[1][1]);
        acc[1][2] = fmaf(x1, wv0.z, acc[1][2]); acc[1][3] = fmaf(x1, wv0.w, acc[1][3]);
        acc[1][4] = fmaf(x1, wv1.x, acc[1][4]); acc[1][5] = fmaf(x1, wv1.y, acc[1][5]);
        acc[1][6] = fmaf(x1, wv1.z, acc[1][6]); acc[1][7] = fmaf(x1, wv1.w, acc[1][7]);
    }
#pragma unroll
    for (int rr = 0; rr < 2; ++rr) {
        int gr = R0 + r0l + rr;
        if (gr >= NN) continue;
        float d = dinv[gr];
        __half2 p0 = __floats2half2_rn(acc[rr][0] * d, acc[rr][1] * d);
        __half2 p1 = __floats2half2_rn(acc[rr][2] * d, acc[rr][3] * d);
        __half2 p2 = __floats2half2_rn(acc[rr][4] * d, acc[rr][5] * d);
        __half2 p3 = __floats2half2_rn(acc[rr][6] * d, acc[rr][7] * d);
        half8 hv; hv.a = p0; hv.b = p1; hv.c = p2; hv.d = p3;
        *(half8*)(Hh2 + (size_t)gr * 32 + c0) = hv;
    }
}

// Layer-2 aggregation: out[i,:] = dinv[i]*(Hh2[i,:] + sum Hh2[src,:]) + b2
template <int NC>
__global__ void k_agg(const __half* __restrict__ Hh, const int* __restrict__ row_ptr,
                      const int* __restrict__ srcsort, const float* __restrict__ dinv,
                      const float* __restrict__ bias, float* __restrict__ out) {
    constexpr int Q = NC / 8;
    int idx = blockIdx.x * blockDim.x + threadIdx.x;
    if (idx >= NN * Q) return;
    int r = idx / Q, q = idx - r * Q;
    half8 sv = *(const half8*)(Hh + (size_t)r * NC + 8 * q);
    float2 f0 = __half22float2(sv.a), f1 = __half22float2(sv.b);
    float2 f2 = __half22float2(sv.c), f3 = __half22float2(sv.d);
    float a0 = f0.x, a1 = f0.y, a2 = f1.x, a3 = f1.y;
    float a4 = f2.x, a5 = f2.y, a6 = f3.x, a7 = f3.y;
    int e0 = row_ptr[r], e1 = row_ptr[r + 1];
    int e = e0;
    for (; e + UN <= e1; e += UN) {
        int ss[UN];
#pragma unroll
        for (int u = 0; u < UN; ++u) ss[u] = srcsort[e + u];
        half8 vv[UN];
#pragma unroll
        for (int u = 0; u < UN; ++u)
            vv[u] = *(const half8*)(Hh + (size_t)ss[u] * NC + 8 * q);
#pragma unroll
        for (int u = 0; u < UN; ++u) {
            float2 g0 = __half22float2(vv[u].a), g1 = __half22float2(vv[u].b);
            float2 g2 = __half22float2(vv[u].c), g3 = __half22float2(vv[u].d);
            a0 += g0.x; a1 += g0.y; a2 += g1.x; a3 += g1.y;
            a4 += g2.x; a5 += g2.y; a6 += g3.x; a7 += g3.y;
        }
    }
    for (; e < e1; ++e) {
        int s = srcsort[e];
        half8 v = *(const half8*)(Hh + (size_t)s * NC + 8 * q);
        float2 g0 = __half22float2(v.a), g1 = __half22float2(v.b);
        float2 g2 = __half22float2(v.c), g3 = __half22float2(v.d);
        a0 += g0.x; a1 += g0.y; a2 += g1.x; a3 += g1.y;
        a4 += g2.x; a5 += g2.y; a6 += g3.x; a7 += g3.y;
    }
    float d = dinv[r];
    const float4* b4 = (const float4*)bias;
    float4 bv0 = b4[2 * q], bv1 = b4[2 * q + 1];
    a0 = fmaf(a0, d, bv0.x); a1 = fmaf(a1, d, bv0.y);
    a2 = fmaf(a2, d, bv0.z); a3 = fmaf(a3, d, bv0.w);
    a4 = fmaf(a4, d, bv1.x); a5 = fmaf(a5, d, bv1.y);
    a6 = fmaf(a6, d, bv1.z); a7 = fmaf(a7, d, bv1.w);
    float4* o4 = (float4*)(out + (size_t)r * NC + 8 * q);
    o4[0] = make_float4(a0, a1, a2, a3);
    o4[1] = make_float4(a4, a5, a6, a7);
}

extern "C" void kernel_launch(void* const* d_in, const int* in_sizes, int n_in,
                              void* d_out, int out_size, void* d_ws, size_t ws_size,
                              hipStream_t stream) {
    const float* x  = (const float*)d_in[0];
    const int*   ei = (const int*)d_in[1];   // [2,NE] int32
    const float* W1 = (const float*)d_in[2];
    const float* b1 = (const float*)d_in[3];
    const float* W2 = (const float*)d_in[4];
    const float* b2 = (const float*)d_in[5];
    float* out = (float*)d_out;

    const int* src = ei;
    const int* dst = ei + NE;

    char* p = (char*)d_ws;
    auto take = [&](size_t elems) { void* q = p; p += ((elems * 4 + 255) & ~255ull); return q; };
    int*    bcnt    = (int*)take(NBUCK);
    int*    bbase   = (int*)take(NBUCK + 1);
    int*    gcursor = (int*)take(NBUCK);
    int*    row_ptr = (int*)take(NN + 1);
    float*  dinv    = (float*)take(NN);
    int*    srcsort = (int*)take(NE);
    __half* Hh      = (__half*)take((size_t)NN * 24);  // NN*48 halves
    int*    packed  = (int*)take(NE);                  // dead after k_bsort
    __half* Hh2     = (__half*)packed;                 // reuse: NN*32 halves fit

    const int B = 256;
    const int GB = (NN + 127) / 128;   // 782 blocks
    // --- dst-sort of edges ---
    k_zero_b<<<1, 1024, 0, stream>>>(bcnt);
    k_hist<<<PART_G, PART_B, 0, stream>>>(dst, bcnt);
    k_scan<<<1, 1024, 0, stream>>>(bcnt, bbase, gcursor, row_ptr);
    k_part<<<PART_G, PART_B, 0, stream>>>(src, dst, gcursor, packed);
    k_bsort<<<NBUCK, 256, 0, stream>>>(packed, bbase, srcsort, row_ptr, dinv);

    // --- layer 1 transform ---
    k_gemm<64, 48, 12><<<GB, 256, 0, stream>>>(x, W1, dinv, Hh, NN);
    // --- fused: layer-1 aggregation + relu/b1 + GEMM2 + dinv ---
    k_fused48<<<GB, 256, 0, stream>>>(Hh, row_ptr, srcsort, dinv, b1, W2, Hh2);
    // --- layer-2 aggregation (+b2) ---
    k_agg<32><<<(NN * 4 + B - 1) / B, B, 0, stream>>>(Hh2, row_ptr, srcsort, dinv, b2, out);
}

// Round 13
// 218.634 us; speedup vs baseline: 3.8631x; 1.0181x over previous
//
#include <hip/hip_runtime.h>
#include <hip/hip_fp16.h>

// GCN 2-layer. Edges partitioned into 782 static dst-buckets (CAP=4096 slots;
// count is Binom(1.6M,1/782): mean 2048, sd 45 -- overflow is 45-sigma),
// then counting-sorted per bucket by (dst_local, src_chunk). Per-node edge
// range packed as rowinfo = (start<<10)|deg (padded srcsort breaks row_ptr
// adjacency at bucket ends). Aggregation gathers 16B half8 chunks from fp16
// features (r9); GEMM2 fused into layer-1 aggregation via LDS tile (r12);
// r13: static buckets kill hist/scan/zero (8->5 kernels) + 384-thr fused
// block (r12 counters: fused48 occupancy 27% -- grid 782 x 4 waves starved
// the gather of MLP).
// r11 lesson: gather width/count neutral -- agg is L2-miss/fabric bound.
// r8 lesson: non-contiguous feature slicing explodes line traffic (1.13 GB).
// r5 lesson: transposed-X LDS staging + full unroll => 850 MB scratch spill.
// out = GCNConv(relu(GCNConv(x,W1,b1)), W2, b2); N=100k, E=1.6M, 64->48->32.

#define NN 100000
#define NE 1600000
#define NPB 128                         // nodes per bucket
#define NBUCK ((NN + NPB - 1) / NPB)    // 782
#define PBITS 17                        // src fits in 17 bits
#define PMASK ((1 << PBITS) - 1)
#define CHB 3                           // log2 src chunks
#define CHS 14                          // chunk = src >> 14
#define NKEY (NPB << CHB)               // 1024 sort keys per bucket
#define PART_B 512
#define EPT 8                           // edges per thread (391 blocks)
#define PART_G ((NE + PART_B * EPT - 1) / (PART_B * EPT))   // 391
#define CAP 4096                        // static slots per bucket
#define UN 8                            // agg edge-loop unroll

struct alignas(8)  half4 { __half2 lo, hi; };
struct alignas(16) half8 { __half2 a, b, c, d; };

// partition edges into static bucket slots; packed = src | (dst_local<<PBITS)
__global__ void k_part(const int* __restrict__ src, const int* __restrict__ dst,
                       int* __restrict__ cursor, int* __restrict__ packed) {
    __shared__ int h[NBUCK];
    __shared__ int base[NBUCK];
    for (int i = threadIdx.x; i < NBUCK; i += blockDim.x) h[i] = 0;
    __syncthreads();
    int ebase = blockIdx.x * (PART_B * EPT);
    for (int k = 0; k < EPT; ++k) {
        int e = ebase + k * PART_B + threadIdx.x;
        if (e < NE) atomicAdd(&h[dst[e] >> 7], 1);
    }
    __syncthreads();
    for (int i = threadIdx.x; i < NBUCK; i += blockDim.x) {
        int c = h[i];
        if (c) base[i] = atomicAdd(&cursor[i], c);
        h[i] = 0;
    }
    __syncthreads();
    for (int k = 0; k < EPT; ++k) {
        int e = ebase + k * PART_B + threadIdx.x;
        if (e < NE) {
            int d = dst[e];
            int b = d >> 7;
            int r = atomicAdd(&h[b], 1);
            packed[(size_t)b * CAP + base[b] + r] = src[e] | ((d & (NPB - 1)) << PBITS);
        }
    }
}

// per-bucket counting sort by (dst_local, src_chunk) -> srcsort (bucket-padded),
// rowinfo = (global_start << 10) | deg, dinv = rsqrt(deg+1).
__global__ void k_bsort(const int* __restrict__ packed, const int* __restrict__ cursor,
                        int* __restrict__ srcsort, unsigned int* __restrict__ rowinfo,
                        float* __restrict__ dinv) {
    __shared__ int stage[CAP];          // 16 KB (sz <= CAP always)
    __shared__ int cnt[NKEY];           // 4 KB
    __shared__ int tsum[256];
    int tid = threadIdx.x, b = blockIdx.x;
    int e0 = b * CAP, sz = cursor[b];
    for (int i = tid; i < NKEY; i += 256) cnt[i] = 0;
    __syncthreads();
    for (int i = tid; i < sz; i += 256) {
        int w = packed[e0 + i];
        stage[i] = w;
        int key = ((w >> PBITS) << CHB) | ((w & PMASK) >> CHS);
        atomicAdd(&cnt[key], 1);
    }
    __syncthreads();
    int k0 = tid * 4;
    int c0 = cnt[k0], c1 = cnt[k0 + 1], c2 = cnt[k0 + 2], c3 = cnt[k0 + 3];
    int loc = c0 + c1 + c2 + c3;
    tsum[tid] = loc;
    __syncthreads();
    for (int off = 1; off < 256; off <<= 1) {
        int v = (tid >= off) ? tsum[tid - off] : 0;
        __syncthreads();
        tsum[tid] += v;
        __syncthreads();
    }
    int base = tsum[tid] - loc;
    cnt[k0]     = base;
    cnt[k0 + 1] = base + c0;
    cnt[k0 + 2] = base + c0 + c1;
    cnt[k0 + 3] = base + c0 + c1 + c2;
    __syncthreads();
    if (tid < NPB) {
        int node = b * NPB + tid;
        int rs = cnt[tid << CHB];
        int re = (tid == NPB - 1) ? sz : cnt[(tid + 1) << CHB];
        if (node < NN) {
            rowinfo[node] = ((unsigned int)(e0 + rs) << 10) | (unsigned int)(re - rs);
            dinv[node] = rsqrtf((float)(re - rs + 1));   // +1 self-loop
        }
    }
    __syncthreads();
    for (int i = tid; i < sz; i += 256) {
        int w = stage[i];
        int key = ((w >> PBITS) << CHB) | ((w & PMASK) >> CHS);
        int p = atomicAdd(&cnt[key], 1);
        srcsort[e0 + p] = w & PMASK;
    }
}

// Register-tiled GEMM1: Hh[M,48] = half( X[M,64] @ W1 * dinv[row] )
template <int K, int NC, int CPT>
__global__ __launch_bounds__(256) void
k_gemm(const float* __restrict__ X, const float* __restrict__ W,
       const float* __restrict__ dinv, __half* __restrict__ Hh, int M) {
    constexpr int CG = NC / CPT;
    constexpr int MT = (256 / CG) * 2;   // 128 rows per block
    constexpr int KF4 = K / 4;
    __shared__ float w[K * NC];
    int tid = threadIdx.x;
    int R0 = blockIdx.x * MT;
    for (int i = tid; i < K * NC; i += 256) w[i] = W[i];
    __syncthreads();

    int tc = tid % CG, tr = tid / CG;
    int r0 = R0 + 2 * tr, r1 = r0 + 1;
    int c0 = tc * CPT;
    bool ok0 = r0 < M, ok1 = r1 < M;
    const float4* X4 = (const float4*)X;
    const float4 z4 = make_float4(0.f, 0.f, 0.f, 0.f);

    float acc[2][CPT];
#pragma unroll
    for (int rr = 0; rr < 2; ++rr)
#pragma unroll
        for (int j = 0; j < CPT; ++j) acc[rr][j] = 0.f;

#pragma unroll 2
    for (int k4 = 0; k4 < KF4; ++k4) {
        float4 xa = ok0 ? X4[(size_t)r0 * KF4 + k4] : z4;
        float4 xb = ok1 ? X4[(size_t)r1 * KF4 + k4] : z4;
        float ar[4] = {xa.x, xa.y, xa.z, xa.w};
        float br[4] = {xb.x, xb.y, xb.z, xb.w};
#pragma unroll
        for (int j = 0; j < 4; ++j) {
            float va = ar[j], vb = br[j];
#pragma unroll
            for (int q = 0; q < CPT / 4; ++q) {
                float4 wv = *(const float4*)&w[(4 * k4 + j) * NC + c0 + 4 * q];
                acc[0][q*4+0] = fmaf(va, wv.x, acc[0][q*4+0]);
                acc[0][q*4+1] = fmaf(va, wv.y, acc[0][q*4+1]);
                acc[0][q*4+2] = fmaf(va, wv.z, acc[0][q*4+2]);
                acc[0][q*4+3] = fmaf(va, wv.w, acc[0][q*4+3]);
                acc[1][q*4+0] = fmaf(vb, wv.x, acc[1][q*4+0]);
                acc[1][q*4+1] = fmaf(vb, wv.y, acc[1][q*4+1]);
                acc[1][q*4+2] = fmaf(vb, wv.z, acc[1][q*4+2]);
                acc[1][q*4+3] = fmaf(vb, wv.w, acc[1][q*4+3]);
            }
        }
    }
#pragma unroll
    for (int rr = 0; rr < 2; ++rr) {
        int gr = r0 + rr;
        if (gr >= M) continue;
        float d = dinv[gr];
#pragma unroll
        for (int q = 0; q < CPT / 4; ++q) {
            __half2 p0 = __floats2half2_rn(acc[rr][q*4+0] * d, acc[rr][q*4+1] * d);
            __half2 p1 = __floats2half2_rn(acc[rr][q*4+2] * d, acc[rr][q*4+3] * d);
            half4 hv; hv.lo = p0; hv.hi = p1;
            *(half4*)(Hh + (size_t)gr * NC + c0 + 4 * q) = hv;
        }
    }
}

// Fused layer-1 aggregation + relu/b1 + GEMM2 + dinv.
// 384 threads (6 waves): phase 1 = 768 (row,chunk) items, 2/thread exact;
// phase 2 = register matvec on tid<256 (2 rows x 8 cols).
__global__ __launch_bounds__(384) void
k_fused48(const __half* __restrict__ Hh, const unsigned int* __restrict__ rowinfo,
          const int* __restrict__ srcsort, const float* __restrict__ dinv,
          const float* __restrict__ b1, const float* __restrict__ W2,
          __half* __restrict__ Hh2) {
    constexpr int ROWS = 128, XS = 49;
    __shared__ float Xs[ROWS * XS];      // 25088 B
    __shared__ float w2[48 * 32];        // 6144 B
    __shared__ float bb[48];
    int tid = threadIdx.x;
    int R0 = blockIdx.x * ROWS;
    for (int i = tid; i < 48 * 32; i += 384) w2[i] = W2[i];
    if (tid < 48) bb[tid] = b1[tid];
    __syncthreads();

    // ---- phase 1: aggregate into Xs ----
    for (int t = tid; t < ROWS * 6; t += 384) {
        int lr = t / 6, q = t - lr * 6;
        int r = R0 + lr;
        if (r >= NN) continue;
        half8 sv = *(const half8*)(Hh + (size_t)r * 48 + 8 * q);   // self-loop
        float2 f0 = __half22float2(sv.a), f1 = __half22float2(sv.b);
        float2 f2 = __half22float2(sv.c), f3 = __half22float2(sv.d);
        float a0 = f0.x, a1 = f0.y, a2 = f1.x, a3 = f1.y;
        float a4 = f2.x, a5 = f2.y, a6 = f3.x, a7 = f3.y;
        unsigned int rp = rowinfo[r];
        int e0 = rp >> 10, e1 = e0 + (rp & 1023);
        int e = e0;
        for (; e + UN <= e1; e += UN) {
            int ss[UN];
#pragma unroll
            for (int u = 0; u < UN; ++u) ss[u] = srcsort[e + u];
            half8 vv[UN];
#pragma unroll
            for (int u = 0; u < UN; ++u)
                vv[u] = *(const half8*)(Hh + (size_t)ss[u] * 48 + 8 * q);
#pragma unroll
            for (int u = 0; u < UN; ++u) {
                float2 g0 = __half22float2(vv[u].a), g1 = __half22float2(vv[u].b);
                float2 g2 = __half22float2(vv[u].c), g3 = __half22float2(vv[u].d);
                a0 += g0.x; a1 += g0.y; a2 += g1.x; a3 += g1.y;
                a4 += g2.x; a5 += g2.y; a6 += g3.x; a7 += g3.y;
            }
        }
        for (; e < e1; ++e) {
            int s = srcsort[e];
            half8 v = *(const half8*)(Hh + (size_t)s * 48 + 8 * q);
            float2 g0 = __half22float2(v.a), g1 = __half22float2(v.b);
            float2 g2 = __half22float2(v.c), g3 = __half22float2(v.d);
            a0 += g0.x; a1 += g0.y; a2 += g1.x; a3 += g1.y;
            a4 += g2.x; a5 += g2.y; a6 += g3.x; a7 += g3.y;
        }
        float d = dinv[r];
        float* xr = &Xs[lr * XS + 8 * q];
        const float* bf = &bb[8 * q];
        xr[0] = fmaxf(fmaf(a0, d, bf[0]), 0.f);
        xr[1] = fmaxf(fmaf(a1, d, bf[1]), 0.f);
        xr[2] = fmaxf(fmaf(a2, d, bf[2]), 0.f);
        xr[3] = fmaxf(fmaf(a3, d, bf[3]), 0.f);
        xr[4] = fmaxf(fmaf(a4, d, bf[4]), 0.f);
        xr[5] = fmaxf(fmaf(a5, d, bf[5]), 0.f);
        xr[6] = fmaxf(fmaf(a6, d, bf[6]), 0.f);
        xr[7] = fmaxf(fmaf(a7, d, bf[7]), 0.f);
    }
    __syncthreads();

    // ---- phase 2: Xs[128,48] @ W2[48,32] -> Hh2 (fp16), tid<256 ----
    if (tid < 256) {
        int tc = tid & 3, tr = tid >> 2;
        int r0l = 2 * tr, c0 = tc * 8;
        float acc[2][8];
#pragma unroll
        for (int rr = 0; rr < 2; ++rr)
#pragma unroll
            for (int j = 0; j < 8; ++j) acc[rr][j] = 0.f;
#pragma unroll 4
        for (int k = 0; k < 48; ++k) {
            float x0 = Xs[r0l * XS + k];
            float x1 = Xs[(r0l + 1) * XS + k];
            float4 wv0 = *(const float4*)&w2[k * 32 + c0];
            float4 wv1 = *(const float4*)&w2[k * 32 + c0 + 4];
            acc[0][0] = fmaf(x0, wv0.x, acc[0][0]); acc[0][1] = fmaf(x0, wv0.y, acc[0][1]);
            acc[0][2] = fmaf(x0, wv0.z, acc[0][2]); acc[0][3] = fmaf(x0, wv0.w, acc[0][3]);
            acc[0][4] = fmaf(x0, wv1.x, acc[0][4]); acc[0][5] = fmaf(x0, wv1.y, acc[0][5]);
            acc[0][6] = fmaf(x0, wv1.z, acc[0][6]); acc[0][7] = fmaf(x0, wv1.w, acc[0][7]);
            acc[1][0] = fmaf(x1, wv0.x, acc[1][0]); acc[1][1] = fmaf(x1, wv0.y, acc[1][1]);
            acc[1][2] = fmaf(x1, wv0.z, acc[1][2]); acc[1][3] = fmaf(x1, wv0.w, acc[1][3]);
            acc[1][4] = fmaf(x1, wv1.x, acc[1][4]); acc[1][5] = fmaf(x1, wv1.y, acc[1][5]);
            acc[1][6] = fmaf(x1, wv1.z, acc[1][6]); acc[1][7] = fmaf(x1, wv1.w, acc[1][7]);
        }
#pragma unroll
        for (int rr = 0; rr < 2; ++rr) {
            int gr = R0 + r0l + rr;
            if (gr >= NN) continue;
            float d = dinv[gr];
            __half2 p0 = __floats2half2_rn(acc[rr][0] * d, acc[rr][1] * d);
            __half2 p1 = __floats2half2_rn(acc[rr][2] * d, acc[rr][3] * d);
            __half2 p2 = __floats2half2_rn(acc[rr][4] * d, acc[rr][5] * d);
            __half2 p3 = __floats2half2_rn(acc[rr][6] * d, acc[rr][7] * d);
            half8 hv; hv.a = p0; hv.b = p1; hv.c = p2; hv.d = p3;
            *(half8*)(Hh2 + (size_t)gr * 32 + c0) = hv;
        }
    }
}

// Layer-2 aggregation: out[i,:] = dinv[i]*(Hh2[i,:] + sum Hh2[src,:]) + b2
template <int NC>
__global__ void k_agg(const __half* __restrict__ Hh, const unsigned int* __restrict__ rowinfo,
                      const int* __restrict__ srcsort, const float* __restrict__ dinv,
                      const float* __restrict__ bias, float* __restrict__ out) {
    constexpr int Q = NC / 8;
    int idx = blockIdx.x * blockDim.x + threadIdx.x;
    if (idx >= NN * Q) return;
    int r = idx / Q, q = idx - r * Q;
    half8 sv = *(const half8*)(Hh + (size_t)r * NC + 8 * q);
    float2 f0 = __half22float2(sv.a), f1 = __half22float2(sv.b);
    float2 f2 = __half22float2(sv.c), f3 = __half22float2(sv.d);
    float a0 = f0.x, a1 = f0.y, a2 = f1.x, a3 = f1.y;
    float a4 = f2.x, a5 = f2.y, a6 = f3.x, a7 = f3.y;
    unsigned int rp = rowinfo[r];
    int e0 = rp >> 10, e1 = e0 + (rp & 1023);
    int e = e0;
    for (; e + UN <= e1; e += UN) {
        int ss[UN];
#pragma unroll
        for (int u = 0; u < UN; ++u) ss[u] = srcsort[e + u];
        half8 vv[UN];
#pragma unroll
        for (int u = 0; u < UN; ++u)
            vv[u] = *(const half8*)(Hh + (size_t)ss[u] * NC + 8 * q);
#pragma unroll
        for (int u = 0; u < UN; ++u) {
            float2 g0 = __half22float2(vv[u].a), g1 = __half22float2(vv[u].b);
            float2 g2 = __half22float2(vv[u].c), g3 = __half22float2(vv[u].d);
            a0 += g0.x; a1 += g0.y; a2 += g1.x; a3 += g1.y;
            a4 += g2.x; a5 += g2.y; a6 += g3.x; a7 += g3.y;
        }
    }
    for (; e < e1; ++e) {
        int s = srcsort[e];
        half8 v = *(const half8*)(Hh + (size_t)s * NC + 8 * q);
        float2 g0 = __half22float2(v.a), g1 = __half22float2(v.b);
        float2 g2 = __half22float2(v.c), g3 = __half22float2(v.d);
        a0 += g0.x; a1 += g0.y; a2 += g1.x; a3 += g1.y;
        a4 += g2.x; a5 += g2.y; a6 += g3.x; a7 += g3.y;
    }
    float d = dinv[r];
    const float4* b4 = (const float4*)bias;
    float4 bv0 = b4[2 * q], bv1 = b4[2 * q + 1];
    a0 = fmaf(a0, d, bv0.x); a1 = fmaf(a1, d, bv0.y);
    a2 = fmaf(a2, d, bv0.z); a3 = fmaf(a3, d, bv0.w);
    a4 = fmaf(a4, d, bv1.x); a5 = fmaf(a5, d, bv1.y);
    a6 = fmaf(a6, d, bv1.z); a7 = fmaf(a7, d, bv1.w);
    float4* o4 = (float4*)(out + (size_t)r * NC + 8 * q);
    o4[0] = make_float4(a0, a1, a2, a3);
    o4[1] = make_float4(a4, a5, a6, a7);
}

extern "C" void kernel_launch(void* const* d_in, const int* in_sizes, int n_in,
                              void* d_out, int out_size, void* d_ws, size_t ws_size,
                              hipStream_t stream) {
    const float* x  = (const float*)d_in[0];
    const int*   ei = (const int*)d_in[1];   // [2,NE] int32
    const float* W1 = (const float*)d_in[2];
    const float* b1 = (const float*)d_in[3];
    const float* W2 = (const float*)d_in[4];
    const float* b2 = (const float*)d_in[5];
    float* out = (float*)d_out;

    const int* src = ei;
    const int* dst = ei + NE;

    char* p = (char*)d_ws;
    auto take = [&](size_t elems) { void* q = p; p += ((elems * 4 + 255) & ~255ull); return q; };
    int*          cursor  = (int*)take(NBUCK);
    unsigned int* rowinfo = (unsigned int*)take(NN);
    float*        dinv    = (float*)take(NN);
    int*          srcsort = (int*)take((size_t)NBUCK * CAP);   // bucket-padded
    __half*       Hh      = (__half*)take((size_t)NN * 24);    // NN*48 halves
    int*          packed  = (int*)take((size_t)NBUCK * CAP);   // dead after bsort
    __half*       Hh2     = (__half*)packed;                   // reuse

    const int B = 256;
    const int GB = (NN + 127) / 128;   // 782 blocks
    // --- dst-sort of edges (static bucket slots) ---
    hipMemsetAsync(cursor, 0, NBUCK * sizeof(int), stream);
    k_part<<<PART_G, PART_B, 0, stream>>>(src, dst, cursor, packed);
    k_bsort<<<NBUCK, 256, 0, stream>>>(packed, cursor, srcsort, rowinfo, dinv);

    // --- layer 1 transform ---
    k_gemm<64, 48, 12><<<GB, 256, 0, stream>>>(x, W1, dinv, Hh, NN);
    // --- fused: layer-1 aggregation + relu/b1 + GEMM2 + dinv ---
    k_fused48<<<GB, 384, 0, stream>>>(Hh, rowinfo, srcsort, dinv, b1, W2, Hh2);
    // --- layer-2 aggregation (+b2) ---
    k_agg<32><<<(NN * 4 + B - 1) / B, B, 0, stream>>>(Hh2, rowinfo, srcsort, dinv, b2, out);
}

// Round 14
// 217.672 us; speedup vs baseline: 3.8802x; 1.0044x over previous
//
#include <hip/hip_runtime.h>
#include <hip/hip_fp16.h>

// GCN 2-layer. Edges partitioned into 782 static dst-buckets (CAP=4096 slots;
// Binom(1.6M,1/782): mean 2048, sd 45 -- overflow is 45-sigma), counting-
// sorted per bucket by (dst_local, src_chunk). rowinfo = (start<<10)|deg.
// Aggregation gathers 16B half8 chunks from fp16 features (r9); GEMM2 fused
// into layer-1 aggregation via LDS tile (r12). r14: fused tile 128->64 rows,
// 256 thr -- r13 showed occupancy is GRID-bound (782 blocks ~ 3/CU, 31.7 KB
// LDS), not wave-bound; doubling blocks + 18.9 KB LDS lifts the ceiling.
// r13 lesson: bigger blocks at fixed grid lower occupancy (384thr: 23%).
// r11 lesson: gather width/count neutral -- agg is L2-miss/fabric bound.
// r8 lesson: non-contiguous feature slicing explodes line traffic (1.13 GB).
// r5 lesson: transposed-X LDS staging + full unroll => 850 MB scratch spill.
// out = GCNConv(relu(GCNConv(x,W1,b1)), W2, b2); N=100k, E=1.6M, 64->48->32.

#define NN 100000
#define NE 1600000
#define NPB 128                         // nodes per bucket
#define NBUCK ((NN + NPB - 1) / NPB)    // 782
#define PBITS 17                        // src fits in 17 bits
#define PMASK ((1 << PBITS) - 1)
#define CHB 3                           // log2 src chunks
#define CHS 14                          // chunk = src >> 14
#define NKEY (NPB << CHB)               // 1024 sort keys per bucket
#define PART_B 512
#define EPT 8                           // edges per thread (391 blocks)
#define PART_G ((NE + PART_B * EPT - 1) / (PART_B * EPT))   // 391
#define CAP 4096                        // static slots per bucket
#define UN 8                            // agg edge-loop unroll

struct alignas(8)  half4 { __half2 lo, hi; };
struct alignas(16) half8 { __half2 a, b, c, d; };

// partition edges into static bucket slots; packed = src | (dst_local<<PBITS)
__global__ void k_part(const int* __restrict__ src, const int* __restrict__ dst,
                       int* __restrict__ cursor, int* __restrict__ packed) {
    __shared__ int h[NBUCK];
    __shared__ int base[NBUCK];
    for (int i = threadIdx.x; i < NBUCK; i += blockDim.x) h[i] = 0;
    __syncthreads();
    int ebase = blockIdx.x * (PART_B * EPT);
    for (int k = 0; k < EPT; ++k) {
        int e = ebase + k * PART_B + threadIdx.x;
        if (e < NE) atomicAdd(&h[dst[e] >> 7], 1);
    }
    __syncthreads();
    for (int i = threadIdx.x; i < NBUCK; i += blockDim.x) {
        int c = h[i];
        if (c) base[i] = atomicAdd(&cursor[i], c);
        h[i] = 0;
    }
    __syncthreads();
    for (int k = 0; k < EPT; ++k) {
        int e = ebase + k * PART_B + threadIdx.x;
        if (e < NE) {
            int d = dst[e];
            int b = d >> 7;
            int r = atomicAdd(&h[b], 1);
            packed[(size_t)b * CAP + base[b] + r] = src[e] | ((d & (NPB - 1)) << PBITS);
        }
    }
}

// per-bucket counting sort by (dst_local, src_chunk) -> srcsort (bucket-padded),
// rowinfo = (global_start << 10) | deg, dinv = rsqrt(deg+1).
__global__ void k_bsort(const int* __restrict__ packed, const int* __restrict__ cursor,
                        int* __restrict__ srcsort, unsigned int* __restrict__ rowinfo,
                        float* __restrict__ dinv) {
    __shared__ int stage[CAP];          // 16 KB (sz <= CAP always)
    __shared__ int cnt[NKEY];           // 4 KB
    __shared__ int tsum[256];
    int tid = threadIdx.x, b = blockIdx.x;
    int e0 = b * CAP, sz = cursor[b];
    for (int i = tid; i < NKEY; i += 256) cnt[i] = 0;
    __syncthreads();
    for (int i = tid; i < sz; i += 256) {
        int w = packed[e0 + i];
        stage[i] = w;
        int key = ((w >> PBITS) << CHB) | ((w & PMASK) >> CHS);
        atomicAdd(&cnt[key], 1);
    }
    __syncthreads();
    int k0 = tid * 4;
    int c0 = cnt[k0], c1 = cnt[k0 + 1], c2 = cnt[k0 + 2], c3 = cnt[k0 + 3];
    int loc = c0 + c1 + c2 + c3;
    tsum[tid] = loc;
    __syncthreads();
    for (int off = 1; off < 256; off <<= 1) {
        int v = (tid >= off) ? tsum[tid - off] : 0;
        __syncthreads();
        tsum[tid] += v;
        __syncthreads();
    }
    int base = tsum[tid] - loc;
    cnt[k0]     = base;
    cnt[k0 + 1] = base + c0;
    cnt[k0 + 2] = base + c0 + c1;
    cnt[k0 + 3] = base + c0 + c1 + c2;
    __syncthreads();
    if (tid < NPB) {
        int node = b * NPB + tid;
        int rs = cnt[tid << CHB];
        int re = (tid == NPB - 1) ? sz : cnt[(tid + 1) << CHB];
        if (node < NN) {
            rowinfo[node] = ((unsigned int)(e0 + rs) << 10) | (unsigned int)(re - rs);
            dinv[node] = rsqrtf((float)(re - rs + 1));   // +1 self-loop
        }
    }
    __syncthreads();
    for (int i = tid; i < sz; i += 256) {
        int w = stage[i];
        int key = ((w >> PBITS) << CHB) | ((w & PMASK) >> CHS);
        int p = atomicAdd(&cnt[key], 1);
        srcsort[e0 + p] = w & PMASK;
    }
}

// Register-tiled GEMM1: Hh[M,48] = half( X[M,64] @ W1 * dinv[row] )
template <int K, int NC, int CPT>
__global__ __launch_bounds__(256) void
k_gemm(const float* __restrict__ X, const float* __restrict__ W,
       const float* __restrict__ dinv, __half* __restrict__ Hh, int M) {
    constexpr int CG = NC / CPT;
    constexpr int MT = (256 / CG) * 2;   // 128 rows per block
    constexpr int KF4 = K / 4;
    __shared__ float w[K * NC];
    int tid = threadIdx.x;
    int R0 = blockIdx.x * MT;
    for (int i = tid; i < K * NC; i += 256) w[i] = W[i];
    __syncthreads();

    int tc = tid % CG, tr = tid / CG;
    int r0 = R0 + 2 * tr, r1 = r0 + 1;
    int c0 = tc * CPT;
    bool ok0 = r0 < M, ok1 = r1 < M;
    const float4* X4 = (const float4*)X;
    const float4 z4 = make_float4(0.f, 0.f, 0.f, 0.f);

    float acc[2][CPT];
#pragma unroll
    for (int rr = 0; rr < 2; ++rr)
#pragma unroll
        for (int j = 0; j < CPT; ++j) acc[rr][j] = 0.f;

#pragma unroll 2
    for (int k4 = 0; k4 < KF4; ++k4) {
        float4 xa = ok0 ? X4[(size_t)r0 * KF4 + k4] : z4;
        float4 xb = ok1 ? X4[(size_t)r1 * KF4 + k4] : z4;
        float ar[4] = {xa.x, xa.y, xa.z, xa.w};
        float br[4] = {xb.x, xb.y, xb.z, xb.w};
#pragma unroll
        for (int j = 0; j < 4; ++j) {
            float va = ar[j], vb = br[j];
#pragma unroll
            for (int q = 0; q < CPT / 4; ++q) {
                float4 wv = *(const float4*)&w[(4 * k4 + j) * NC + c0 + 4 * q];
                acc[0][q*4+0] = fmaf(va, wv.x, acc[0][q*4+0]);
                acc[0][q*4+1] = fmaf(va, wv.y, acc[0][q*4+1]);
                acc[0][q*4+2] = fmaf(va, wv.z, acc[0][q*4+2]);
                acc[0][q*4+3] = fmaf(va, wv.w, acc[0][q*4+3]);
                acc[1][q*4+0] = fmaf(vb, wv.x, acc[1][q*4+0]);
                acc[1][q*4+1] = fmaf(vb, wv.y, acc[1][q*4+1]);
                acc[1][q*4+2] = fmaf(vb, wv.z, acc[1][q*4+2]);
                acc[1][q*4+3] = fmaf(vb, wv.w, acc[1][q*4+3]);
            }
        }
    }
#pragma unroll
    for (int rr = 0; rr < 2; ++rr) {
        int gr = r0 + rr;
        if (gr >= M) continue;
        float d = dinv[gr];
#pragma unroll
        for (int q = 0; q < CPT / 4; ++q) {
            __half2 p0 = __floats2half2_rn(acc[rr][q*4+0] * d, acc[rr][q*4+1] * d);
            __half2 p1 = __floats2half2_rn(acc[rr][q*4+2] * d, acc[rr][q*4+3] * d);
            half4 hv; hv.lo = p0; hv.hi = p1;
            *(half4*)(Hh + (size_t)gr * NC + c0 + 4 * q) = hv;
        }
    }
}

// Fused layer-1 aggregation + relu/b1 + GEMM2 + dinv.
// 64-row tile, 256 threads: phase 1 = 384 (row,chunk) items (1.5/thread);
// phase 2 = 1 row x 8 cols per thread, all threads active.
__global__ __launch_bounds__(256) void
k_fused48(const __half* __restrict__ Hh, const unsigned int* __restrict__ rowinfo,
          const int* __restrict__ srcsort, const float* __restrict__ dinv,
          const float* __restrict__ b1, const float* __restrict__ W2,
          __half* __restrict__ Hh2) {
    constexpr int ROWS = 64, XS = 49;
    __shared__ float Xs[ROWS * XS];      // 12544 B
    __shared__ float w2[48 * 32];        // 6144 B
    __shared__ float bb[48];             // total ~18.9 KB -> 8 blocks/CU
    int tid = threadIdx.x;
    int R0 = blockIdx.x * ROWS;
    for (int i = tid; i < 48 * 32; i += 256) w2[i] = W2[i];
    if (tid < 48) bb[tid] = b1[tid];
    __syncthreads();

    // ---- phase 1: aggregate into Xs ----
    for (int t = tid; t < ROWS * 6; t += 256) {
        int lr = t / 6, q = t - lr * 6;
        int r = R0 + lr;
        if (r >= NN) continue;
        half8 sv = *(const half8*)(Hh + (size_t)r * 48 + 8 * q);   // self-loop
        float2 f0 = __half22float2(sv.a), f1 = __half22float2(sv.b);
        float2 f2 = __half22float2(sv.c), f3 = __half22float2(sv.d);
        float a0 = f0.x, a1 = f0.y, a2 = f1.x, a3 = f1.y;
        float a4 = f2.x, a5 = f2.y, a6 = f3.x, a7 = f3.y;
        unsigned int rp = rowinfo[r];
        int e0 = rp >> 10, e1 = e0 + (rp & 1023);
        int e = e0;
        for (; e + UN <= e1; e += UN) {
            int ss[UN];
#pragma unroll
            for (int u = 0; u < UN; ++u) ss[u] = srcsort[e + u];
            half8 vv[UN];
#pragma unroll
            for (int u = 0; u < UN; ++u)
                vv[u] = *(const half8*)(Hh + (size_t)ss[u] * 48 + 8 * q);
#pragma unroll
            for (int u = 0; u < UN; ++u) {
                float2 g0 = __half22float2(vv[u].a), g1 = __half22float2(vv[u].b);
                float2 g2 = __half22float2(vv[u].c), g3 = __half22float2(vv[u].d);
                a0 += g0.x; a1 += g0.y; a2 += g1.x; a3 += g1.y;
                a4 += g2.x; a5 += g2.y; a6 += g3.x; a7 += g3.y;
            }
        }
        for (; e < e1; ++e) {
            int s = srcsort[e];
            half8 v = *(const half8*)(Hh + (size_t)s * 48 + 8 * q);
            float2 g0 = __half22float2(v.a), g1 = __half22float2(v.b);
            float2 g2 = __half22float2(v.c), g3 = __half22float2(v.d);
            a0 += g0.x; a1 += g0.y; a2 += g1.x; a3 += g1.y;
            a4 += g2.x; a5 += g2.y; a6 += g3.x; a7 += g3.y;
        }
        float d = dinv[r];
        float* xr = &Xs[lr * XS + 8 * q];
        const float* bf = &bb[8 * q];
        xr[0] = fmaxf(fmaf(a0, d, bf[0]), 0.f);
        xr[1] = fmaxf(fmaf(a1, d, bf[1]), 0.f);
        xr[2] = fmaxf(fmaf(a2, d, bf[2]), 0.f);
        xr[3] = fmaxf(fmaf(a3, d, bf[3]), 0.f);
        xr[4] = fmaxf(fmaf(a4, d, bf[4]), 0.f);
        xr[5] = fmaxf(fmaf(a5, d, bf[5]), 0.f);
        xr[6] = fmaxf(fmaf(a6, d, bf[6]), 0.f);
        xr[7] = fmaxf(fmaf(a7, d, bf[7]), 0.f);
    }
    __syncthreads();

    // ---- phase 2: Xs[64,48] @ W2[48,32] -> Hh2 (fp16); 1 row x 8 cols/thread ----
    int tc = tid & 3, tr = tid >> 2;     // tr in [0,64)
    int c0 = tc * 8;
    float acc[8];
#pragma unroll
    for (int j = 0; j < 8; ++j) acc[j] = 0.f;
#pragma unroll 4
    for (int k = 0; k < 48; ++k) {
        float x0 = Xs[tr * XS + k];
        float4 wv0 = *(const float4*)&w2[k * 32 + c0];
        float4 wv1 = *(const float4*)&w2[k * 32 + c0 + 4];
        acc[0] = fmaf(x0, wv0.x, acc[0]); acc[1] = fmaf(x0, wv0.y, acc[1]);
        acc[2] = fmaf(x0, wv0.z, acc[2]); acc[3] = fmaf(x0, wv0.w, acc[3]);
        acc[4] = fmaf(x0, wv1.x, acc[4]); acc[5] = fmaf(x0, wv1.y, acc[5]);
        acc[6] = fmaf(x0, wv1.z, acc[6]); acc[7] = fmaf(x0, wv1.w, acc[7]);
    }
    int gr = R0 + tr;
    if (gr < NN) {
        float d = dinv[gr];
        __half2 p0 = __floats2half2_rn(acc[0] * d, acc[1] * d);
        __half2 p1 = __floats2half2_rn(acc[2] * d, acc[3] * d);
        __half2 p2 = __floats2half2_rn(acc[4] * d, acc[5] * d);
        __half2 p3 = __floats2half2_rn(acc[6] * d, acc[7] * d);
        half8 hv; hv.a = p0; hv.b = p1; hv.c = p2; hv.d = p3;
        *(half8*)(Hh2 + (size_t)gr * 32 + c0) = hv;
    }
}

// Layer-2 aggregation: out[i,:] = dinv[i]*(Hh2[i,:] + sum Hh2[src,:]) + b2
template <int NC>
__global__ void k_agg(const __half* __restrict__ Hh, const unsigned int* __restrict__ rowinfo,
                      const int* __restrict__ srcsort, const float* __restrict__ dinv,
                      const float* __restrict__ bias, float* __restrict__ out) {
    constexpr int Q = NC / 8;
    int idx = blockIdx.x * blockDim.x + threadIdx.x;
    if (idx >= NN * Q) return;
    int r = idx / Q, q = idx - r * Q;
    half8 sv = *(const half8*)(Hh + (size_t)r * NC + 8 * q);
    float2 f0 = __half22float2(sv.a), f1 = __half22float2(sv.b);
    float2 f2 = __half22float2(sv.c), f3 = __half22float2(sv.d);
    float a0 = f0.x, a1 = f0.y, a2 = f1.x, a3 = f1.y;
    float a4 = f2.x, a5 = f2.y, a6 = f3.x, a7 = f3.y;
    unsigned int rp = rowinfo[r];
    int e0 = rp >> 10, e1 = e0 + (rp & 1023);
    int e = e0;
    for (; e + UN <= e1; e += UN) {
        int ss[UN];
#pragma unroll
        for (int u = 0; u < UN; ++u) ss[u] = srcsort[e + u];
        half8 vv[UN];
#pragma unroll
        for (int u = 0; u < UN; ++u)
            vv[u] = *(const half8*)(Hh + (size_t)ss[u] * NC + 8 * q);
#pragma unroll
        for (int u = 0; u < UN; ++u) {
            float2 g0 = __half22float2(vv[u].a), g1 = __half22float2(vv[u].b);
            float2 g2 = __half22float2(vv[u].c), g3 = __half22float2(vv[u].d);
            a0 += g0.x; a1 += g0.y; a2 += g1.x; a3 += g1.y;
            a4 += g2.x; a5 += g2.y; a6 += g3.x; a7 += g3.y;
        }
    }
    for (; e < e1; ++e) {
        int s = srcsort[e];
        half8 v = *(const half8*)(Hh + (size_t)s * NC + 8 * q);
        float2 g0 = __half22float2(v.a), g1 = __half22float2(v.b);
        float2 g2 = __half22float2(v.c), g3 = __half22float2(v.d);
        a0 += g0.x; a1 += g0.y; a2 += g1.x; a3 += g1.y;
        a4 += g2.x; a5 += g2.y; a6 += g3.x; a7 += g3.y;
    }
    float d = dinv[r];
    const float4* b4 = (const float4*)bias;
    float4 bv0 = b4[2 * q], bv1 = b4[2 * q + 1];
    a0 = fmaf(a0, d, bv0.x); a1 = fmaf(a1, d, bv0.y);
    a2 = fmaf(a2, d, bv0.z); a3 = fmaf(a3, d, bv0.w);
    a4 = fmaf(a4, d, bv1.x); a5 = fmaf(a5, d, bv1.y);
    a6 = fmaf(a6, d, bv1.z); a7 = fmaf(a7, d, bv1.w);
    float4* o4 = (float4*)(out + (size_t)r * NC + 8 * q);
    o4[0] = make_float4(a0, a1, a2, a3);
    o4[1] = make_float4(a4, a5, a6, a7);
}

extern "C" void kernel_launch(void* const* d_in, const int* in_sizes, int n_in,
                              void* d_out, int out_size, void* d_ws, size_t ws_size,
                              hipStream_t stream) {
    const float* x  = (const float*)d_in[0];
    const int*   ei = (const int*)d_in[1];   // [2,NE] int32
    const float* W1 = (const float*)d_in[2];
    const float* b1 = (const float*)d_in[3];
    const float* W2 = (const float*)d_in[4];
    const float* b2 = (const float*)d_in[5];
    float* out = (float*)d_out;

    const int* src = ei;
    const int* dst = ei + NE;

    char* p = (char*)d_ws;
    auto take = [&](size_t elems) { void* q = p; p += ((elems * 4 + 255) & ~255ull); return q; };
    int*          cursor  = (int*)take(NBUCK);
    unsigned int* rowinfo = (unsigned int*)take(NN);
    float*        dinv    = (float*)take(NN);
    int*          srcsort = (int*)take((size_t)NBUCK * CAP);   // bucket-padded
    __half*       Hh      = (__half*)take((size_t)NN * 24);    // NN*48 halves
    int*          packed  = (int*)take((size_t)NBUCK * CAP);   // dead after bsort
    __half*       Hh2     = (__half*)packed;                   // reuse

    const int B = 256;
    const int GB = (NN + 127) / 128;   // 782 blocks (gemm1)
    const int GF = (NN + 63) / 64;     // 1563 blocks (fused)
    // --- dst-sort of edges (static bucket slots) ---
    hipMemsetAsync(cursor, 0, NBUCK * sizeof(int), stream);
    k_part<<<PART_G, PART_B, 0, stream>>>(src, dst, cursor, packed);
    k_bsort<<<NBUCK, 256, 0, stream>>>(packed, cursor, srcsort, rowinfo, dinv);

    // --- layer 1 transform ---
    k_gemm<64, 48, 12><<<GB, 256, 0, stream>>>(x, W1, dinv, Hh, NN);
    // --- fused: layer-1 aggregation + relu/b1 + GEMM2 + dinv ---
    k_fused48<<<GF, 256, 0, stream>>>(Hh, rowinfo, srcsort, dinv, b1, W2, Hh2);
    // --- layer-2 aggregation (+b2) ---
    k_agg<32><<<(NN * 4 + B - 1) / B, B, 0, stream>>>(Hh2, rowinfo, srcsort, dinv, b2, out);
}

// Round 15
// 207.452 us; speedup vs baseline: 4.0714x; 1.0493x over previous
//
#include <hip/hip_runtime.h>
#include <hip/hip_fp16.h>

// GCN 2-layer. Edges partitioned into 782 static dst-buckets (CAP=4096;
// Binom(1.6M,1/782): mean 2048, sd 45 -- overflow is 45-sigma), counting-
// sorted per bucket by (dst_local, src_chunk). rowinfo = (start<<10)|deg.
// Aggregation gathers 16B half8 chunks from fp16 features (r9); GEMM2 fused
// into layer-1 aggregation via LDS tile (r12, 128-row geometry -- best
// measured). r15: masked full-width UN-batches kill the serial gather tail
// (r14 insight: per-row latency was dominated by up to 7 DEPENDENT tail
// gathers; occupancy/width/bytes all proved neutral r11-r14).
// r13 lesson: bigger blocks at fixed grid lower occupancy.
// r11 lesson: gather width/count neutral -- agg is latency-chain bound.
// r8 lesson: non-contiguous feature slicing explodes line traffic (1.13 GB).
// r5 lesson: transposed-X LDS staging + full unroll => 850 MB scratch spill.
// out = GCNConv(relu(GCNConv(x,W1,b1)), W2, b2); N=100k, E=1.6M, 64->48->32.

#define NN 100000
#define NE 1600000
#define NPB 128                         // nodes per bucket
#define NBUCK ((NN + NPB - 1) / NPB)    // 782
#define PBITS 17                        // src fits in 17 bits
#define PMASK ((1 << PBITS) - 1)
#define CHB 3                           // log2 src chunks
#define CHS 14                          // chunk = src >> 14
#define NKEY (NPB << CHB)               // 1024 sort keys per bucket
#define PART_B 512
#define EPT 8                           // edges per thread (391 blocks)
#define PART_G ((NE + PART_B * EPT - 1) / (PART_B * EPT))   // 391
#define CAP 4096                        // static slots per bucket
#define UN 8                            // agg edge-loop unroll (masked batches)

struct alignas(8)  half4 { __half2 lo, hi; };
struct alignas(16) half8 { __half2 a, b, c, d; };

// partition edges into static bucket slots; packed = src | (dst_local<<PBITS)
__global__ void k_part(const int* __restrict__ src, const int* __restrict__ dst,
                       int* __restrict__ cursor, int* __restrict__ packed) {
    __shared__ int h[NBUCK];
    __shared__ int base[NBUCK];
    for (int i = threadIdx.x; i < NBUCK; i += blockDim.x) h[i] = 0;
    __syncthreads();
    int ebase = blockIdx.x * (PART_B * EPT);
    for (int k = 0; k < EPT; ++k) {
        int e = ebase + k * PART_B + threadIdx.x;
        if (e < NE) atomicAdd(&h[dst[e] >> 7], 1);
    }
    __syncthreads();
    for (int i = threadIdx.x; i < NBUCK; i += blockDim.x) {
        int c = h[i];
        if (c) base[i] = atomicAdd(&cursor[i], c);
        h[i] = 0;
    }
    __syncthreads();
    for (int k = 0; k < EPT; ++k) {
        int e = ebase + k * PART_B + threadIdx.x;
        if (e < NE) {
            int d = dst[e];
            int b = d >> 7;
            int r = atomicAdd(&h[b], 1);
            packed[(size_t)b * CAP + base[b] + r] = src[e] | ((d & (NPB - 1)) << PBITS);
        }
    }
}

// per-bucket counting sort by (dst_local, src_chunk) -> srcsort (bucket-padded),
// rowinfo = (global_start << 10) | deg, dinv = rsqrt(deg+1).
__global__ void k_bsort(const int* __restrict__ packed, const int* __restrict__ cursor,
                        int* __restrict__ srcsort, unsigned int* __restrict__ rowinfo,
                        float* __restrict__ dinv) {
    __shared__ int stage[CAP];          // 16 KB (sz <= CAP always)
    __shared__ int cnt[NKEY];           // 4 KB
    __shared__ int tsum[256];
    int tid = threadIdx.x, b = blockIdx.x;
    int e0 = b * CAP, sz = cursor[b];
    for (int i = tid; i < NKEY; i += 256) cnt[i] = 0;
    __syncthreads();
    for (int i = tid; i < sz; i += 256) {
        int w = packed[e0 + i];
        stage[i] = w;
        int key = ((w >> PBITS) << CHB) | ((w & PMASK) >> CHS);
        atomicAdd(&cnt[key], 1);
    }
    __syncthreads();
    int k0 = tid * 4;
    int c0 = cnt[k0], c1 = cnt[k0 + 1], c2 = cnt[k0 + 2], c3 = cnt[k0 + 3];
    int loc = c0 + c1 + c2 + c3;
    tsum[tid] = loc;
    __syncthreads();
    for (int off = 1; off < 256; off <<= 1) {
        int v = (tid >= off) ? tsum[tid - off] : 0;
        __syncthreads();
        tsum[tid] += v;
        __syncthreads();
    }
    int base = tsum[tid] - loc;
    cnt[k0]     = base;
    cnt[k0 + 1] = base + c0;
    cnt[k0 + 2] = base + c0 + c1;
    cnt[k0 + 3] = base + c0 + c1 + c2;
    __syncthreads();
    if (tid < NPB) {
        int node = b * NPB + tid;
        int rs = cnt[tid << CHB];
        int re = (tid == NPB - 1) ? sz : cnt[(tid + 1) << CHB];
        if (node < NN) {
            rowinfo[node] = ((unsigned int)(e0 + rs) << 10) | (unsigned int)(re - rs);
            dinv[node] = rsqrtf((float)(re - rs + 1));   // +1 self-loop
        }
    }
    __syncthreads();
    for (int i = tid; i < sz; i += 256) {
        int w = stage[i];
        int key = ((w >> PBITS) << CHB) | ((w & PMASK) >> CHS);
        int p = atomicAdd(&cnt[key], 1);
        srcsort[e0 + p] = w & PMASK;
    }
}

// Register-tiled GEMM1: Hh[M,48] = half( X[M,64] @ W1 * dinv[row] )
template <int K, int NC, int CPT>
__global__ __launch_bounds__(256) void
k_gemm(const float* __restrict__ X, const float* __restrict__ W,
       const float* __restrict__ dinv, __half* __restrict__ Hh, int M) {
    constexpr int CG = NC / CPT;
    constexpr int MT = (256 / CG) * 2;   // 128 rows per block
    constexpr int KF4 = K / 4;
    __shared__ float w[K * NC];
    int tid = threadIdx.x;
    int R0 = blockIdx.x * MT;
    for (int i = tid; i < K * NC; i += 256) w[i] = W[i];
    __syncthreads();

    int tc = tid % CG, tr = tid / CG;
    int r0 = R0 + 2 * tr, r1 = r0 + 1;
    int c0 = tc * CPT;
    bool ok0 = r0 < M, ok1 = r1 < M;
    const float4* X4 = (const float4*)X;
    const float4 z4 = make_float4(0.f, 0.f, 0.f, 0.f);

    float acc[2][CPT];
#pragma unroll
    for (int rr = 0; rr < 2; ++rr)
#pragma unroll
        for (int j = 0; j < CPT; ++j) acc[rr][j] = 0.f;

#pragma unroll 2
    for (int k4 = 0; k4 < KF4; ++k4) {
        float4 xa = ok0 ? X4[(size_t)r0 * KF4 + k4] : z4;
        float4 xb = ok1 ? X4[(size_t)r1 * KF4 + k4] : z4;
        float ar[4] = {xa.x, xa.y, xa.z, xa.w};
        float br[4] = {xb.x, xb.y, xb.z, xb.w};
#pragma unroll
        for (int j = 0; j < 4; ++j) {
            float va = ar[j], vb = br[j];
#pragma unroll
            for (int q = 0; q < CPT / 4; ++q) {
                float4 wv = *(const float4*)&w[(4 * k4 + j) * NC + c0 + 4 * q];
                acc[0][q*4+0] = fmaf(va, wv.x, acc[0][q*4+0]);
                acc[0][q*4+1] = fmaf(va, wv.y, acc[0][q*4+1]);
                acc[0][q*4+2] = fmaf(va, wv.z, acc[0][q*4+2]);
                acc[0][q*4+3] = fmaf(va, wv.w, acc[0][q*4+3]);
                acc[1][q*4+0] = fmaf(vb, wv.x, acc[1][q*4+0]);
                acc[1][q*4+1] = fmaf(vb, wv.y, acc[1][q*4+1]);
                acc[1][q*4+2] = fmaf(vb, wv.z, acc[1][q*4+2]);
                acc[1][q*4+3] = fmaf(vb, wv.w, acc[1][q*4+3]);
            }
        }
    }
#pragma unroll
    for (int rr = 0; rr < 2; ++rr) {
        int gr = r0 + rr;
        if (gr >= M) continue;
        float d = dinv[gr];
#pragma unroll
        for (int q = 0; q < CPT / 4; ++q) {
            __half2 p0 = __floats2half2_rn(acc[rr][q*4+0] * d, acc[rr][q*4+1] * d);
            __half2 p1 = __floats2half2_rn(acc[rr][q*4+2] * d, acc[rr][q*4+3] * d);
            half4 hv; hv.lo = p0; hv.hi = p1;
            *(half4*)(Hh + (size_t)gr * NC + c0 + 4 * q) = hv;
        }
    }
}

// Fused layer-1 aggregation + relu/b1 + GEMM2 + dinv. 128-row tile, 256 thr
// (r12 geometry). Phase 1 edge loops use masked full-width UN-batches: all
// gathers independent, no serial tail (lanes past deg clamp to srcsort[e0]
// and contribute with mask 0 via fmaf).
__global__ __launch_bounds__(256) void
k_fused48(const __half* __restrict__ Hh, const unsigned int* __restrict__ rowinfo,
          const int* __restrict__ srcsort, const float* __restrict__ dinv,
          const float* __restrict__ b1, const float* __restrict__ W2,
          __half* __restrict__ Hh2) {
    constexpr int ROWS = 128, XS = 49;
    __shared__ float Xs[ROWS * XS];      // 25088 B
    __shared__ float w2[48 * 32];        // 6144 B
    __shared__ float bb[48];
    int tid = threadIdx.x;
    int R0 = blockIdx.x * ROWS;
    for (int i = tid; i < 48 * 32; i += 256) w2[i] = W2[i];
    if (tid < 48) bb[tid] = b1[tid];
    __syncthreads();

    // ---- phase 1: aggregate into Xs (3 (row,chunk) items per thread) ----
    for (int t = tid; t < ROWS * 6; t += 256) {
        int lr = t / 6, q = t - lr * 6;
        int r = R0 + lr;
        if (r >= NN) continue;
        half8 sv = *(const half8*)(Hh + (size_t)r * 48 + 8 * q);   // self-loop
        float2 f0 = __half22float2(sv.a), f1 = __half22float2(sv.b);
        float2 f2 = __half22float2(sv.c), f3 = __half22float2(sv.d);
        float a0 = f0.x, a1 = f0.y, a2 = f1.x, a3 = f1.y;
        float a4 = f2.x, a5 = f2.y, a6 = f3.x, a7 = f3.y;
        unsigned int rp = rowinfo[r];
        int e0 = rp >> 10, e1 = e0 + (int)(rp & 1023);
        for (int e = e0; e < e1; e += UN) {
            int ss[UN]; float ms[UN];
#pragma unroll
            for (int u = 0; u < UN; ++u) {
                int ee = e + u;
                bool ok = ee < e1;
                ss[u] = srcsort[ok ? ee : e0];
                ms[u] = ok ? 1.f : 0.f;
            }
            half8 vv[UN];
#pragma unroll
            for (int u = 0; u < UN; ++u)
                vv[u] = *(const half8*)(Hh + (size_t)ss[u] * 48 + 8 * q);
#pragma unroll
            for (int u = 0; u < UN; ++u) {
                float2 g0 = __half22float2(vv[u].a), g1 = __half22float2(vv[u].b);
                float2 g2 = __half22float2(vv[u].c), g3 = __half22float2(vv[u].d);
                float m = ms[u];
                a0 = fmaf(g0.x, m, a0); a1 = fmaf(g0.y, m, a1);
                a2 = fmaf(g1.x, m, a2); a3 = fmaf(g1.y, m, a3);
                a4 = fmaf(g2.x, m, a4); a5 = fmaf(g2.y, m, a5);
                a6 = fmaf(g3.x, m, a6); a7 = fmaf(g3.y, m, a7);
            }
        }
        float d = dinv[r];
        float* xr = &Xs[lr * XS + 8 * q];
        const float* bf = &bb[8 * q];
        xr[0] = fmaxf(fmaf(a0, d, bf[0]), 0.f);
        xr[1] = fmaxf(fmaf(a1, d, bf[1]), 0.f);
        xr[2] = fmaxf(fmaf(a2, d, bf[2]), 0.f);
        xr[3] = fmaxf(fmaf(a3, d, bf[3]), 0.f);
        xr[4] = fmaxf(fmaf(a4, d, bf[4]), 0.f);
        xr[5] = fmaxf(fmaf(a5, d, bf[5]), 0.f);
        xr[6] = fmaxf(fmaf(a6, d, bf[6]), 0.f);
        xr[7] = fmaxf(fmaf(a7, d, bf[7]), 0.f);
    }
    __syncthreads();

    // ---- phase 2: Xs[128,48] @ W2[48,32] -> Hh2 (fp16); 2 rows x 8 cols ----
    int tc = tid & 3, tr = tid >> 2;
    int r0l = 2 * tr, c0 = tc * 8;
    float acc[2][8];
#pragma unroll
    for (int rr = 0; rr < 2; ++rr)
#pragma unroll
        for (int j = 0; j < 8; ++j) acc[rr][j] = 0.f;
#pragma unroll 4
    for (int k = 0; k < 48; ++k) {
        float x0 = Xs[r0l * XS + k];
        float x1 = Xs[(r0l + 1) * XS + k];
        float4 wv0 = *(const float4*)&w2[k * 32 + c0];
        float4 wv1 = *(const float4*)&w2[k * 32 + c0 + 4];
        acc[0][0] = fmaf(x0, wv0.x, acc[0][0]); acc[0][1] = fmaf(x0, wv0.y, acc[0][1]);
        acc[0][2] = fmaf(x0, wv0.z, acc[0][2]); acc[0][3] = fmaf(x0, wv0.w, acc[0][3]);
        acc[0][4] = fmaf(x0, wv1.x, acc[0][4]); acc[0][5] = fmaf(x0, wv1.y, acc[0][5]);
        acc[0][6] = fmaf(x0, wv1.z, acc[0][6]); acc[0][7] = fmaf(x0, wv1.w, acc[0][7]);
        acc[1][0] = fmaf(x1, wv0.x, acc[1][0]); acc[1][1] = fmaf(x1, wv0.y, acc[1][1]);
        acc[1][2] = fmaf(x1, wv0.z, acc[1][2]); acc[1][3] = fmaf(x1, wv0.w, acc[1][3]);
        acc[1][4] = fmaf(x1, wv1.x, acc[1][4]); acc[1][5] = fmaf(x1, wv1.y, acc[1][5]);
        acc[1][6] = fmaf(x1, wv1.z, acc[1][6]); acc[1][7] = fmaf(x1, wv1.w, acc[1][7]);
    }
#pragma unroll
    for (int rr = 0; rr < 2; ++rr) {
        int gr = R0 + r0l + rr;
        if (gr >= NN) continue;
        float d = dinv[gr];
        __half2 p0 = __floats2half2_rn(acc[rr][0] * d, acc[rr][1] * d);
        __half2 p1 = __floats2half2_rn(acc[rr][2] * d, acc[rr][3] * d);
        __half2 p2 = __floats2half2_rn(acc[rr][4] * d, acc[rr][5] * d);
        __half2 p3 = __floats2half2_rn(acc[rr][6] * d, acc[rr][7] * d);
        half8 hv; hv.a = p0; hv.b = p1; hv.c = p2; hv.d = p3;
        *(half8*)(Hh2 + (size_t)gr * 32 + c0) = hv;
    }
}

// Layer-2 aggregation: out[i,:] = dinv[i]*(Hh2[i,:] + sum Hh2[src,:]) + b2
// Masked full-width UN-batches (no serial tail).
template <int NC>
__global__ void k_agg(const __half* __restrict__ Hh, const unsigned int* __restrict__ rowinfo,
                      const int* __restrict__ srcsort, const float* __restrict__ dinv,
                      const float* __restrict__ bias, float* __restrict__ out) {
    constexpr int Q = NC / 8;
    int idx = blockIdx.x * blockDim.x + threadIdx.x;
    if (idx >= NN * Q) return;
    int r = idx / Q, q = idx - r * Q;
    half8 sv = *(const half8*)(Hh + (size_t)r * NC + 8 * q);
    float2 f0 = __half22float2(sv.a), f1 = __half22float2(sv.b);
    float2 f2 = __half22float2(sv.c), f3 = __half22float2(sv.d);
    float a0 = f0.x, a1 = f0.y, a2 = f1.x, a3 = f1.y;
    float a4 = f2.x, a5 = f2.y, a6 = f3.x, a7 = f3.y;
    unsigned int rp = rowinfo[r];
    int e0 = rp >> 10, e1 = e0 + (int)(rp & 1023);
    for (int e = e0; e < e1; e += UN) {
        int ss[UN]; float ms[UN];
#pragma unroll
        for (int u = 0; u < UN; ++u) {
            int ee = e + u;
            bool ok = ee < e1;
            ss[u] = srcsort[ok ? ee : e0];
            ms[u] = ok ? 1.f : 0.f;
        }
        half8 vv[UN];
#pragma unroll
        for (int u = 0; u < UN; ++u)
            vv[u] = *(const half8*)(Hh + (size_t)ss[u] * NC + 8 * q);
#pragma unroll
        for (int u = 0; u < UN; ++u) {
            float2 g0 = __half22float2(vv[u].a), g1 = __half22float2(vv[u].b);
            float2 g2 = __half22float2(vv[u].c), g3 = __half22float2(vv[u].d);
            float m = ms[u];
            a0 = fmaf(g0.x, m, a0); a1 = fmaf(g0.y, m, a1);
            a2 = fmaf(g1.x, m, a2); a3 = fmaf(g1.y, m, a3);
            a4 = fmaf(g2.x, m, a4); a5 = fmaf(g2.y, m, a5);
            a6 = fmaf(g3.x, m, a6); a7 = fmaf(g3.y, m, a7);
        }
    }
    float d = dinv[r];
    const float4* b4 = (const float4*)bias;
    float4 bv0 = b4[2 * q], bv1 = b4[2 * q + 1];
    a0 = fmaf(a0, d, bv0.x); a1 = fmaf(a1, d, bv0.y);
    a2 = fmaf(a2, d, bv0.z); a3 = fmaf(a3, d, bv0.w);
    a4 = fmaf(a4, d, bv1.x); a5 = fmaf(a5, d, bv1.y);
    a6 = fmaf(a6, d, bv1.z); a7 = fmaf(a7, d, bv1.w);
    float4* o4 = (float4*)(out + (size_t)r * NC + 8 * q);
    o4[0] = make_float4(a0, a1, a2, a3);
    o4[1] = make_float4(a4, a5, a6, a7);
}

extern "C" void kernel_launch(void* const* d_in, const int* in_sizes, int n_in,
                              void* d_out, int out_size, void* d_ws, size_t ws_size,
                              hipStream_t stream) {
    const float* x  = (const float*)d_in[0];
    const int*   ei = (const int*)d_in[1];   // [2,NE] int32
    const float* W1 = (const float*)d_in[2];
    const float* b1 = (const float*)d_in[3];
    const float* W2 = (const float*)d_in[4];
    const float* b2 = (const float*)d_in[5];
    float* out = (float*)d_out;

    const int* src = ei;
    const int* dst = ei + NE;

    char* p = (char*)d_ws;
    auto take = [&](size_t elems) { void* q = p; p += ((elems * 4 + 255) & ~255ull); return q; };
    int*          cursor  = (int*)take(NBUCK);
    unsigned int* rowinfo = (unsigned int*)take(NN);
    float*        dinv    = (float*)take(NN);
    int*          srcsort = (int*)take((size_t)NBUCK * CAP);   // bucket-padded
    __half*       Hh      = (__half*)take((size_t)NN * 24);    // NN*48 halves
    int*          packed  = (int*)take((size_t)NBUCK * CAP);   // dead after bsort
    __half*       Hh2     = (__half*)packed;                   // reuse

    const int B = 256;
    const int GB = (NN + 127) / 128;   // 782 blocks
    // --- dst-sort of edges (static bucket slots) ---
    hipMemsetAsync(cursor, 0, NBUCK * sizeof(int), stream);
    k_part<<<PART_G, PART_B, 0, stream>>>(src, dst, cursor, packed);
    k_bsort<<<NBUCK, 256, 0, stream>>>(packed, cursor, srcsort, rowinfo, dinv);

    // --- layer 1 transform ---
    k_gemm<64, 48, 12><<<GB, 256, 0, stream>>>(x, W1, dinv, Hh, NN);
    // --- fused: layer-1 aggregation + relu/b1 + GEMM2 + dinv ---
    k_fused48<<<GB, 256, 0, stream>>>(Hh, rowinfo, srcsort, dinv, b1, W2, Hh2);
    // --- layer-2 aggregation (+b2) ---
    k_agg<32><<<(NN * 4 + B - 1) / B, B, 0, stream>>>(Hh2, rowinfo, srcsort, dinv, b2, out);
}